// Round 14
// baseline (1002.836 us; speedup 1.0000x reference)
//
#include <hip/hip_runtime.h>
#include <hip/hip_bf16.h>

#define NNODES 16384
#define NEDGES 262144
#define IND    128
#define HD     256
#define OUTDIM 256
#define LAYERS 4
#define NHEADS 8
#define OCD    32
#define NGRAPH 64
#define NBATCH 256

typedef __hip_bfloat16 bf16;
typedef __attribute__((ext_vector_type(8))) short bf16x8;
typedef __attribute__((ext_vector_type(4))) short s16x4;
typedef __attribute__((ext_vector_type(4))) float f32x4;

__device__ __forceinline__ short bfbits(float v) {
    bf16 h = __float2bfloat16(v);
    return *(short*)&h;
}
__device__ __forceinline__ float b2f(short s) {
    return __uint_as_float(((unsigned)(unsigned short)s) << 16);
}

// blocked bf16 layout: X[(row/64)*KC + col/8][row%64][col%8], KC = cols/8.
// Gives DMA-coalesced staging AND conflict-free ds_read_b128 fragments.
__device__ __forceinline__ size_t bidx(int row, int col, int KC) {
    return ((size_t)((row >> 6) * KC + (col >> 3)) << 9) + ((row & 63) << 3) + (col & 7);
}

// direct global->LDS DMA, 16 B/lane; lds base wave-uniform, global addr per-lane
__device__ __forceinline__ void gload_lds16(const short* g, short* l) {
    __builtin_amdgcn_global_load_lds(
        (const __attribute__((address_space(1))) void*)g,
        (__attribute__((address_space(3))) void*)l, 16, 0, 0);
}

// ---------------- merged prep: zeros + all weight converts (blocked layout) ----
#define PREP_TOTAL (32768 + NNODES*IND + IND*HD + LAYERS*1024*HD + LAYERS*1024 \
                    + LAYERS*HD*HD + LAYERS*HD*2*HD + LAYERS*2*HD*HD + HD*OUTDIM)
__global__ void prep_kernel(const float* __restrict__ x0, const float* __restrict__ wi,
                            const float* __restrict__ inw, const float* __restrict__ wg,
                            const float* __restrict__ inb, const float* __restrict__ ow,
                            const float* __restrict__ mw1, const float* __restrict__ mw2,
                            const float* __restrict__ wo,
                            short* __restrict__ x016, short* __restrict__ wi_t,
                            short* __restrict__ wcomb, float* __restrict__ cbias,
                            short* __restrict__ ow_c, short* __restrict__ mw1_t,
                            short* __restrict__ mw2_t, short* __restrict__ wo_t,
                            int* __restrict__ cnt, int* __restrict__ fill)
{
    int i = blockIdx.x * blockDim.x + threadIdx.x;
    if (i < 32768) {
        if (i < NNODES) cnt[i] = 0; else fill[i - NNODES] = 0;
        return;
    }
    i -= 32768;
    if (i < NNODES * IND) {                // x0 -> blocked [N,128], KC=16
        int row = i / IND, col = i % IND;
        x016[bidx(row, col, 16)] = bfbits(x0[i]);
        return;
    }
    i -= NNODES * IND;
    if (i < IND * HD) {                    // wi [128,256] -> B[n=256][k=128], KC=16
        int k = i / HD, n = i % HD;
        wi_t[bidx(n, k, 16)] = bfbits(wi[i]);
        return;
    }
    i -= IND * HD;
    if (i < LAYERS * 1024 * HD) {          // wcomb rows 0..767=inw, 768..1023=wg^T, KC=32
        int l = i >> 18, r = (i >> 8) & 1023, k = i & 255;
        float v = (r < 768) ? inw[(size_t)l * 768 * 256 + r * 256 + k]
                            : wg[(size_t)l * 256 * 256 + k * 256 + (r - 768)];
        wcomb[((size_t)l << 18) + bidx(r, k, 32)] = bfbits(v);
        return;
    }
    i -= LAYERS * 1024 * HD;
    if (i < LAYERS * 1024) {               // cbias (fp32, unchanged)
        int l = i >> 10, c = i & 1023;
        cbias[i] = (c < 768) ? inb[l * 768 + c] : 0.f;
        return;
    }
    i -= LAYERS * 1024;
    if (i < LAYERS * HD * HD) {            // ow: B[r=256][k=256] as-is, KC=32
        int l = i >> 16, rem = i & 65535, r = rem >> 8, k = rem & 255;
        ow_c[((size_t)l << 16) + bidx(r, k, 32)] = bfbits(ow[i]);
        return;
    }
    i -= LAYERS * HD * HD;
    if (i < LAYERS * HD * 2 * HD) {        // mw1 [k=256][n=512] -> B[n][k], KC=32
        int l = i / (HD * 2 * HD), rem = i % (HD * 2 * HD);
        int k = rem / (2 * HD), n = rem % (2 * HD);
        mw1_t[(size_t)l * HD * 2 * HD + bidx(n, k, 32)] = bfbits(mw1[i]);
        return;
    }
    i -= LAYERS * HD * 2 * HD;
    if (i < LAYERS * 2 * HD * HD) {        // mw2 [k=512][n=256] -> B[n][k], KC=64
        int l = i / (2 * HD * HD), rem = i % (2 * HD * HD);
        int k = rem / HD, n = rem % HD;
        mw2_t[(size_t)l * 2 * HD * HD + bidx(n, k, 64)] = bfbits(mw2[i]);
        return;
    }
    i -= LAYERS * 2 * HD * HD;
    if (i < HD * OUTDIM) {                 // wo [k=256][n=256] -> B[n][k], KC=32
        int k = i / OUTDIM, n = i % OUTDIM;
        wo_t[bidx(n, k, 32)] = bfbits(wo[i]);
    }
}

// ---------------- CSR build: histogram -> scan -> scatter ----------------------
__global__ void hist_kernel(const int* __restrict__ dst, int* __restrict__ cnt)
{
    int e = blockIdx.x * blockDim.x + threadIdx.x;
    if (e < NEDGES) atomicAdd(&cnt[dst[e]], 1);
}

__global__ void scan_kernel(const int* __restrict__ cnt, int* __restrict__ row_ptr)
{
    __shared__ int part[256];
    int t = threadIdx.x;
    const int PER = NNODES / 256;
    int base = t * PER;
    int s = 0;
    for (int i = 0; i < PER; i++) s += cnt[base + i];
    part[t] = s;
    __syncthreads();
    for (int off = 1; off < 256; off <<= 1) {
        int v = (t >= off) ? part[t - off] : 0;
        __syncthreads();
        part[t] += v;
        __syncthreads();
    }
    int run = (t == 0) ? 0 : part[t - 1];
    for (int i = 0; i < PER; i++) { row_ptr[base + i] = run; run += cnt[base + i]; }
    if (t == 255) row_ptr[NNODES] = run;
}

__global__ void scatter_kernel(const int* __restrict__ src, const int* __restrict__ dst,
                               const int* __restrict__ row_ptr, int* __restrict__ fill,
                               int* __restrict__ srcs)
{
    int e = blockIdx.x * blockDim.x + threadIdx.x;
    if (e >= NEDGES) return;
    int d = dst[e];
    int pos = row_ptr[d] + atomicAdd(&fill[d], 1);
    srcs[pos] = src[e];
}

// ---------------- GAT per-node attention scores (blocked xq16, cols 768+) ------
__global__ void gat_scores_kernel(const short* __restrict__ xq16,
                                  const float* __restrict__ asrc, const float* __restrict__ adst,
                                  float* __restrict__ ssrc, float* __restrict__ sdst)
{
    int i = blockIdx.x * blockDim.x + threadIdx.x;   // n*NHEADS + h
    if (i >= NNODES * NHEADS) return;
    int n = i >> 3, h = i & 7;
    float s1 = 0.f, s2 = 0.f;
#pragma unroll
    for (int g = 0; g < 4; g++) {
        bf16x8 v8 = *(const bf16x8*)&xq16[bidx(n, 768 + h * OCD + g * 8, 128)];
#pragma unroll
        for (int j = 0; j < 8; j++) {
            float v = b2f(v8[j]);
            int d = g * 8 + j;
            s1 += v * asrc[h * OCD + d];
            s2 += v * adst[h * OCD + d];
        }
    }
    ssrc[i] = s1;
    sdst[i] = s2;
}

// ---------------- fused GAT softmax + aggregation + LayerNorm ------------------
__global__ __launch_bounds__(256)
void gat_agg_ln_kernel(const int* __restrict__ row_ptr, const int* __restrict__ srcs,
                       const float* __restrict__ ssrc, const float* __restrict__ sdst,
                       const short* __restrict__ xq16, const float* __restrict__ xcur,
                       const float* __restrict__ colbias, const float* __restrict__ gamma,
                       const float* __restrict__ beta, float* __restrict__ out)
{
    int wave = threadIdx.x >> 6, lane = threadIdx.x & 63;
    int n = blockIdx.x * 4 + wave;
    int c0 = lane << 2;            // 4 channels per lane
    int h = c0 >> 5;               // head of all 4 channels
    int start = row_ptr[n];
    int deg = row_ptr[n + 1] - start;
    float sd = sdst[n * NHEADS + h];

    float ax = 0.f, ay = 0.f, az = 0.f, aw = 0.f, l = 0.f;
    int j = 0;
    for (; j + 4 <= deg; j += 4) {
        int e0 = srcs[start + j + 0], e1 = srcs[start + j + 1];
        int e2 = srcs[start + j + 2], e3 = srcs[start + j + 3];
        s16x4 r0 = *(const s16x4*)&xq16[bidx(e0, 768 + c0, 128)];
        s16x4 r1 = *(const s16x4*)&xq16[bidx(e1, 768 + c0, 128)];
        s16x4 r2 = *(const s16x4*)&xq16[bidx(e2, 768 + c0, 128)];
        s16x4 r3 = *(const s16x4*)&xq16[bidx(e3, 768 + c0, 128)];
        float a0 = ssrc[e0 * NHEADS + h] + sd; a0 = a0 > 0.f ? a0 : 0.2f * a0;
        float a1 = ssrc[e1 * NHEADS + h] + sd; a1 = a1 > 0.f ? a1 : 0.2f * a1;
        float a2 = ssrc[e2 * NHEADS + h] + sd; a2 = a2 > 0.f ? a2 : 0.2f * a2;
        float a3 = ssrc[e3 * NHEADS + h] + sd; a3 = a3 > 0.f ? a3 : 0.2f * a3;
        float p0 = __expf(a0), p1 = __expf(a1), p2 = __expf(a2), p3 = __expf(a3);
        l += (p0 + p1) + (p2 + p3);
        ax += p0 * b2f(r0[0]) + p1 * b2f(r1[0]) + p2 * b2f(r2[0]) + p3 * b2f(r3[0]);
        ay += p0 * b2f(r0[1]) + p1 * b2f(r1[1]) + p2 * b2f(r2[1]) + p3 * b2f(r3[1]);
        az += p0 * b2f(r0[2]) + p1 * b2f(r1[2]) + p2 * b2f(r2[2]) + p3 * b2f(r3[2]);
        aw += p0 * b2f(r0[3]) + p1 * b2f(r1[3]) + p2 * b2f(r2[3]) + p3 * b2f(r3[3]);
    }
    for (; j < deg; j++) {
        int e0 = srcs[start + j];
        s16x4 r0 = *(const s16x4*)&xq16[bidx(e0, 768 + c0, 128)];
        float a0 = ssrc[e0 * NHEADS + h] + sd; a0 = a0 > 0.f ? a0 : 0.2f * a0;
        float p0 = __expf(a0);
        l += p0;
        ax += p0 * b2f(r0[0]); ay += p0 * b2f(r0[1]);
        az += p0 * b2f(r0[2]); aw += p0 * b2f(r0[3]);
    }
    float invl = deg ? 1.f / l : 0.f;
    size_t base = (size_t)n * HD + c0;
    float4 x4 = *(const float4*)&xcur[base];
    float4 cb = *(const float4*)&colbias[c0];
    float4 v;
    v.x = ax * invl + x4.x + cb.x;
    v.y = ay * invl + x4.y + cb.y;
    v.z = az * invl + x4.z + cb.z;
    v.w = aw * invl + x4.w + cb.w;
    float s = v.x + v.y + v.z + v.w;
    float q = v.x * v.x + v.y * v.y + v.z * v.z + v.w * v.w;
#pragma unroll
    for (int off = 1; off < 64; off <<= 1) {
        s += __shfl_xor(s, off);
        q += __shfl_xor(q, off);
    }
    float mean = s * (1.f / HD);
    float var  = fmaxf(q * (1.f / HD) - mean * mean, 0.f);
    float inv  = rsqrtf(var + 1e-5f);
    float4 g  = *(const float4*)&gamma[c0];
    float4 bt = *(const float4*)&beta[c0];
    float4 y;
    y.x = (v.x - mean) * inv * g.x + bt.x;
    y.y = (v.y - mean) * inv * g.y + bt.y;
    y.z = (v.z - mean) * inv * g.z + bt.z;
    y.w = (v.w - mean) * inv * g.w + bt.w;
    *(float4*)&out[base] = y;
}

// ---------------- bf16 MFMA GEMM (blocked A/B): C = A@B^T (+bias)(+resid)(relu)-
// Wave wid stages kchunk (4t+wid): 1 KB contiguous DMA per instruction, LDS
// slots in row order -> fragment ds_read_b128 is 2-way (free). Swapped-operand
// mfma -> vectorized epilogue; C16 written in blocked layout.
#define GBM 128
#define GBK 32

template<int TN>
__global__ __launch_bounds__(256)
void gemm_mfma_kernel(const short* __restrict__ A16, const short* __restrict__ B16,
                      const float* __restrict__ bias, const float* __restrict__ resid,
                      float* __restrict__ Cf, short* __restrict__ C16,
                      int M, int Nc, int K, int relu)
{
    constexpr int NTF = TN / 32;          // n-frags per wave
    __shared__ short As[GBM * GBK];       // 512 slots
    __shared__ short Bs[TN * GBK];
    int tid = threadIdx.x;
    int wid = tid >> 6, lane = tid & 63;
    int quad = lane >> 4, l16 = lane & 15;
    int wm = wid >> 1, wn = wid & 1;
    int rowBase = blockIdx.y * GBM;
    int colBase = blockIdx.x * TN;
    int KC = K >> 3;

    f32x4 acc[4][NTF];
#pragma unroll
    for (int mt = 0; mt < 4; mt++)
#pragma unroll
        for (int nt = 0; nt < NTF; nt++) acc[mt][nt] = (f32x4)(0.f);

    // blocked staging: base = (rowGroup*KC + kchunk) * 512 + lane*8 (1 KB/wave)
    const short* Ag0 = A16 + (((size_t)(blockIdx.y * 2 + 0) * KC + wid) << 9) + lane * 8;
    const short* Ag1 = A16 + (((size_t)(blockIdx.y * 2 + 1) * KC + wid) << 9) + lane * 8;
    const short* Bg0 = B16 + (((size_t)((colBase >> 6) + 0) * KC + wid) << 9) + lane * 8;
    const short* Bg1 = (TN == 128) ?
        B16 + (((size_t)((colBase >> 6) + 1) * KC + wid) << 9) + lane * 8 : nullptr;
    short* AsD0 = As + (wid * 128 + 0) * 8;
    short* AsD1 = As + (wid * 128 + 64) * 8;
    short* BsD0 = Bs + (wid * TN) * 8;
    short* BsD1 = Bs + (wid * TN + 64) * 8;

    for (int t = 0; t < (K >> 5); t++) {
        gload_lds16(Ag0 + t * 2048, AsD0);
        gload_lds16(Ag1 + t * 2048, AsD1);
        gload_lds16(Bg0 + t * 2048, BsD0);
        if (TN == 128) gload_lds16(Bg1 + t * 2048, BsD1);
        __syncthreads();
        bf16x8 aF[4], bF[NTF];
#pragma unroll
        for (int mt = 0; mt < 4; mt++)
            aF[mt] = *(bf16x8*)&As[(quad * 128 + wm * 64 + mt * 16 + l16) * 8];
#pragma unroll
        for (int nt = 0; nt < NTF; nt++)
            bF[nt] = *(bf16x8*)&Bs[(quad * TN + wn * (TN / 2) + nt * 16 + l16) * 8];
#pragma unroll
        for (int mt = 0; mt < 4; mt++)
#pragma unroll
            for (int nt = 0; nt < NTF; nt++)
                acc[mt][nt] = __builtin_amdgcn_mfma_f32_16x16x32_bf16(
                    bF[nt], aF[mt], acc[mt][nt], 0, 0, 0);   // swapped operands
        __syncthreads();
    }

    // epilogue: row = ...+l16, cols = ...+quad*4 (contiguous 4)
#pragma unroll
    for (int mt = 0; mt < 4; mt++) {
        int row = rowBase + wm * 64 + mt * 16 + l16;
#pragma unroll
        for (int nt = 0; nt < NTF; nt++) {
            int col0 = colBase + wn * (TN / 2) + nt * 16 + quad * 4;
            f32x4 v = acc[mt][nt];
            if (bias) {
                float4 b4 = *(const float4*)&bias[col0];
                v[0] += b4.x; v[1] += b4.y; v[2] += b4.z; v[3] += b4.w;
            }
            if (resid) {
                float4 r4 = *(const float4*)&resid[(size_t)row * Nc + col0];
                v[0] += r4.x; v[1] += r4.y; v[2] += r4.z; v[3] += r4.w;
            }
            if (relu) {
                v[0] = fmaxf(v[0], 0.f); v[1] = fmaxf(v[1], 0.f);
                v[2] = fmaxf(v[2], 0.f); v[3] = fmaxf(v[3], 0.f);
            }
            if (Cf) {
                float4 o; o.x = v[0]; o.y = v[1]; o.z = v[2]; o.w = v[3];
                *(float4*)&Cf[(size_t)row * Nc + col0] = o;
            }
            if (C16) {
                s16x4 o;
                o[0] = bfbits(v[0]); o[1] = bfbits(v[1]);
                o[2] = bfbits(v[2]); o[3] = bfbits(v[3]);
                *(s16x4*)&C16[bidx(row, col0, Nc >> 3)] = o;
            }
        }
    }
}

// ---------------- fused GEMM + residual + LayerNorm (+postadd) -----------------
// 64-row x 256-col tile; blocked A/B; row LN reduce = 2 shuffles.
__global__ __launch_bounds__(256)
void gemm_ln_kernel(const short* __restrict__ A16, const short* __restrict__ B16,
                    const float* __restrict__ bias, const float* __restrict__ resid,
                    const float* __restrict__ gamma, const float* __restrict__ beta,
                    const float* __restrict__ postadd,
                    float* __restrict__ outf, short* __restrict__ out16, int K)
{
    __shared__ short As[64 * GBK];        // 256 slots
    __shared__ short Bs[256 * GBK];       // 1024 slots
    int tid = threadIdx.x;
    int wid = tid >> 6, lane = tid & 63;
    int quad = lane >> 4, l16 = lane & 15;
    int rowBase = blockIdx.y * 64;
    int KC = K >> 3;

    f32x4 acc[16];
#pragma unroll
    for (int nt = 0; nt < 16; nt++) acc[nt] = (f32x4)(0.f);

    const short* Ag  = A16 + (((size_t)blockIdx.y * KC + wid) << 9) + lane * 8;
    const short* Bg0 = B16 + (((size_t)0 * KC + wid) << 9) + lane * 8;
    const short* Bg1 = B16 + (((size_t)1 * KC + wid) << 9) + lane * 8;
    const short* Bg2 = B16 + (((size_t)2 * KC + wid) << 9) + lane * 8;
    const short* Bg3 = B16 + (((size_t)3 * KC + wid) << 9) + lane * 8;
    short* AsD  = As + (wid * 64) * 8;
    short* BsD0 = Bs + (wid * 256 + 0) * 8;
    short* BsD1 = Bs + (wid * 256 + 64) * 8;
    short* BsD2 = Bs + (wid * 256 + 128) * 8;
    short* BsD3 = Bs + (wid * 256 + 192) * 8;

    for (int t = 0; t < (K >> 5); t++) {
        gload_lds16(Ag + t * 2048, AsD);
        gload_lds16(Bg0 + t * 2048, BsD0);
        gload_lds16(Bg1 + t * 2048, BsD1);
        gload_lds16(Bg2 + t * 2048, BsD2);
        gload_lds16(Bg3 + t * 2048, BsD3);
        __syncthreads();
        bf16x8 aF = *(bf16x8*)&As[(quad * 64 + wid * 16 + l16) * 8];
#pragma unroll
        for (int nt = 0; nt < 16; nt++) {
            bf16x8 bF = *(bf16x8*)&Bs[(quad * 256 + nt * 16 + l16) * 8];
            acc[nt] = __builtin_amdgcn_mfma_f32_16x16x32_bf16(bF, aF, acc[nt], 0, 0, 0);
        }
        __syncthreads();
    }

    int row = rowBase + wid * 16 + l16;
    float s = 0.f, q = 0.f;
#pragma unroll
    for (int nt = 0; nt < 16; nt++) {
        int col0 = nt * 16 + quad * 4;
        f32x4 v = acc[nt];
        float4 b4 = *(const float4*)&bias[col0];
        float4 r4 = *(const float4*)&resid[(size_t)row * HD + col0];
        v[0] += b4.x + r4.x; v[1] += b4.y + r4.y;
        v[2] += b4.z + r4.z; v[3] += b4.w + r4.w;
        acc[nt] = v;
        s += (v[0] + v[1]) + (v[2] + v[3]);
        q += (v[0] * v[0] + v[1] * v[1]) + (v[2] * v[2] + v[3] * v[3]);
    }
    s += __shfl_xor(s, 16); s += __shfl_xor(s, 32);
    q += __shfl_xor(q, 16); q += __shfl_xor(q, 32);
    float mean = s * (1.f / HD);
    float var  = fmaxf(q * (1.f / HD) - mean * mean, 0.f);
    float inv  = rsqrtf(var + 1e-5f);
#pragma unroll
    for (int nt = 0; nt < 16; nt++) {
        int col0 = nt * 16 + quad * 4;
        f32x4 v = acc[nt];
        float4 g4 = *(const float4*)&gamma[col0];
        float4 bt = *(const float4*)&beta[col0];
        float4 y;
        y.x = (v[0] - mean) * inv * g4.x + bt.x;
        y.y = (v[1] - mean) * inv * g4.y + bt.y;
        y.z = (v[2] - mean) * inv * g4.z + bt.z;
        y.w = (v[3] - mean) * inv * g4.w + bt.w;
        if (postadd) {
            float4 p4 = *(const float4*)&postadd[(size_t)row * HD + col0];
            y.x += p4.x; y.y += p4.y; y.z += p4.z; y.w += p4.w;
        }
        *(float4*)&outf[(size_t)row * HD + col0] = y;
        s16x4 o;
        o[0] = bfbits(y.x); o[1] = bfbits(y.y); o[2] = bfbits(y.z); o[3] = bfbits(y.w);
        *(s16x4*)&out16[bidx(row, col0, 32)] = o;
    }
}

// ---------------- LayerNorm: wave-per-row, float4, shuffle-only ----------------
__global__ __launch_bounds__(256)
void ln4_kernel(const float* __restrict__ in, const float* __restrict__ res,
                const float* __restrict__ gamma, const float* __restrict__ beta,
                const float* __restrict__ postadd,
                float* __restrict__ outf, short* __restrict__ out16)
{
    int wave = threadIdx.x >> 6, lane = threadIdx.x & 63;
    int row = blockIdx.x * 4 + wave;
    size_t base = (size_t)row * HD + lane * 4;
    float4 v = *(const float4*)&in[base];
    if (res) {
        float4 r = *(const float4*)&res[base];
        v.x += r.x; v.y += r.y; v.z += r.z; v.w += r.w;
    }
    float s = v.x + v.y + v.z + v.w;
    float q = v.x * v.x + v.y * v.y + v.z * v.z + v.w * v.w;
#pragma unroll
    for (int off = 1; off < 64; off <<= 1) {
        s += __shfl_xor(s, off);
        q += __shfl_xor(q, off);
    }
    float mean = s * (1.f / HD);
    float var  = fmaxf(q * (1.f / HD) - mean * mean, 0.f);
    float inv  = rsqrtf(var + 1e-5f);
    float4 g  = *(const float4*)&gamma[lane * 4];
    float4 bt = *(const float4*)&beta[lane * 4];
    float4 y;
    y.x = (v.x - mean) * inv * g.x + bt.x;
    y.y = (v.y - mean) * inv * g.y + bt.y;
    y.z = (v.z - mean) * inv * g.z + bt.z;
    y.w = (v.w - mean) * inv * g.w + bt.w;
    if (postadd) {
        float4 p = *(const float4*)&postadd[base];
        y.x += p.x; y.y += p.y; y.z += p.z; y.w += p.w;
    }
    if (outf) *(float4*)&outf[base] = y;
    if (out16) {
        s16x4 o;
        o[0] = bfbits(y.x); o[1] = bfbits(y.y); o[2] = bfbits(y.z); o[3] = bfbits(y.w);
        *(s16x4*)&out16[bidx(row, lane * 4, 32)] = o;
    }
}

// ---------------- MFMA per-graph MHA (blocked qkv16, KC=128) -------------------
#define PSTR 72                       // slot stride 9 (x16B) == 1 mod 8 -> conflict-free
__global__ __launch_bounds__(256)
void mha_mfma_kernel(const short* __restrict__ qkv16, short* __restrict__ o16)
{
    __shared__ short smem[4 * 64 * PSTR + 32 * PSTR];   // P (4w x 64q x 64k) + V^T (32d x 64k)
    short* VT = smem + 4 * 64 * PSTR;

    int b = blockIdx.x, h = blockIdx.y;
    int tid = threadIdx.x;
    int wid = tid >> 6, lane = tid & 63;
    int quad = lane >> 4, l16 = lane & 15;
    int base = b * NBATCH;
    int qrow0 = wid * 64;
    short* Pme = smem + wid * 64 * PSTR;

    const float scale2 = 0.17677669529663687f * 1.4426950408889634f; // 1/sqrt(32)*log2(e)

    bf16x8 qA[4];
#pragma unroll
    for (int mt = 0; mt < 4; mt++)
        qA[mt] = *(const bf16x8*)&qkv16[bidx(base + qrow0 + mt * 16 + l16, h * 32 + quad * 8, 128)];

    f32x4 accO[4][2];
#pragma unroll
    for (int mt = 0; mt < 4; mt++)
#pragma unroll
        for (int dt = 0; dt < 2; dt++) accO[mt][dt] = (f32x4)(0.f);
    float lsum[4][4];
#pragma unroll
    for (int mt = 0; mt < 4; mt++)
#pragma unroll
        for (int r = 0; r < 4; r++) lsum[mt][r] = 0.f;

    for (int c = 0; c < 4; c++) {                  // 4 key-chunks of 64
        __syncthreads();
        {
            int key = tid >> 2, dq = (tid & 3) * 8;
            bf16x8 v = *(const bf16x8*)&qkv16[bidx(base + c * 64 + key, 512 + h * 32 + dq, 128)];
#pragma unroll
            for (int j = 0; j < 8; j++) VT[(dq + j) * PSTR + key] = v[j];
        }
        __syncthreads();
        bf16x8 kB[4];
#pragma unroll
        for (int kt = 0; kt < 4; kt++)
            kB[kt] = *(const bf16x8*)&qkv16[bidx(base + c * 64 + kt * 16 + l16, 256 + h * 32 + quad * 8, 128)];
#pragma unroll
        for (int mt = 0; mt < 4; mt++) {
#pragma unroll
            for (int kt = 0; kt < 4; kt++) {
                f32x4 s = __builtin_amdgcn_mfma_f32_16x16x32_bf16(qA[mt], kB[kt], (f32x4)(0.f), 0, 0, 0);
#pragma unroll
                for (int r = 0; r < 4; r++) {
                    float p = exp2f(s[r] * scale2);
                    lsum[mt][r] += p;
                    Pme[(mt * 16 + quad * 4 + r) * PSTR + kt * 16 + l16] = bfbits(p);
                }
            }
        }
        __syncthreads();
#pragma unroll
        for (int mt = 0; mt < 4; mt++) {
#pragma unroll
            for (int ks = 0; ks < 2; ks++) {
                bf16x8 pA = *(bf16x8*)&Pme[(mt * 16 + l16) * PSTR + ks * 32 + quad * 8];
#pragma unroll
                for (int dt = 0; dt < 2; dt++) {
                    bf16x8 vB = *(bf16x8*)&VT[(dt * 16 + l16) * PSTR + ks * 32 + quad * 8];
                    accO[mt][dt] = __builtin_amdgcn_mfma_f32_16x16x32_bf16(pA, vB, accO[mt][dt], 0, 0, 0);
                }
            }
        }
    }
#pragma unroll
    for (int mt = 0; mt < 4; mt++)
#pragma unroll
        for (int r = 0; r < 4; r++) {
            float v = lsum[mt][r];
            v += __shfl_xor(v, 1);
            v += __shfl_xor(v, 2);
            v += __shfl_xor(v, 4);
            v += __shfl_xor(v, 8);
            lsum[mt][r] = v;
        }
#pragma unroll
    for (int mt = 0; mt < 4; mt++)
#pragma unroll
        for (int dt = 0; dt < 2; dt++)
#pragma unroll
            for (int r = 0; r < 4; r++) {
                int row = base + qrow0 + mt * 16 + quad * 4 + r;
                int col = h * 32 + dt * 16 + l16;
                o16[bidx(row, col, 32)] = bfbits(accO[mt][dt][r] / lsum[mt][r]);
            }
}

// ------------------------------------------------------------------------------
extern "C" void kernel_launch(void* const* d_in, const int* in_sizes, int n_in,
                              void* d_out, int out_size, void* d_ws, size_t ws_size,
                              hipStream_t stream)
{
    const float* x0   = (const float*)d_in[0];
    const int*   ei   = (const int*)d_in[1];
    const float* wi   = (const float*)d_in[2];
    const float* bi   = (const float*)d_in[3];
    const float* wg   = (const float*)d_in[4];
    const float* asrc = (const float*)d_in[5];
    const float* adst = (const float*)d_in[6];
    const float* bg   = (const float*)d_in[7];
    const float* g1   = (const float*)d_in[8];
    const float* b1   = (const float*)d_in[9];
    const float* inw  = (const float*)d_in[10];
    const float* inb  = (const float*)d_in[11];
    const float* ow   = (const float*)d_in[12];
    const float* ob   = (const float*)d_in[13];
    const float* g2   = (const float*)d_in[14];
    const float* b2   = (const float*)d_in[15];
    const float* mw1  = (const float*)d_in[16];
    const float* mb1  = (const float*)d_in[17];
    const float* mw2  = (const float*)d_in[18];
    const float* mb2  = (const float*)d_in[19];
    const float* g3   = (const float*)d_in[20];
    const float* b3   = (const float*)d_in[21];
    const float* gf   = (const float*)d_in[22];
    const float* bf_  = (const float*)d_in[23];
    const float* wo   = (const float*)d_in[24];
    const float* bo   = (const float*)d_in[25];

    const int* srcI = ei;
    const int* dstI = ei + NEDGES;

    // ---- workspace layout ----
    const size_t NH = (size_t)NNODES * HD;           // 4,194,304
    float* ws   = (float*)d_ws;
    float* xcur = ws;                // [N,H] fp32
    float* xw   = xcur + NH;         // [N,H] fp32 (layout stability)
    float* hbuf = xw + NH;           // [N,H] fp32
    float* obuf = hbuf + NH;         // [N,H] fp32
    float* qkvb = obuf + NH;         // region reused as bf16 [N,1024] blocked
    int*   srcs    = (int*)(qkvb + 3 * NH);          // [E]
    int*   row_ptr = srcs + NEDGES;                  // [N+1]
    int*   cnt     = row_ptr + NNODES + 1;           // [N]
    int*   fill    = cnt + NNODES;                   // [N]
    float* ssrc    = (float*)(fill + NNODES);        // [N,8]
    float* sdst    = ssrc + (size_t)NNODES * NHEADS; // [N,8]
    // bf16 (short) region — ALL bf16 tensors in blocked layout
    short* xq16   = (short*)qkvb;                    // [N,1024] blocked KC=128
    short* x016   = (short*)(sdst + (size_t)NNODES * NHEADS);  // [N,128] KC=16
    short* xcur16 = x016 + (size_t)NNODES * IND;     // [N,H] KC=32
    short* b16a   = xcur16 + NH;                     // [N,H] KC=32
    short* hid16  = b16a + NH;                       // [N,2H] KC=64
    // bf16 weights (blocked)
    short* wi_t  = hid16 + 2 * NH;                         // [256,128] KC=16
    short* wcomb = wi_t + (size_t)HD * IND;                // 4x[1024,256] KC=32
    short* ow_c  = wcomb + (size_t)LAYERS * 1024 * HD;     // 4x[256,256] KC=32
    short* mw1_t = ow_c + (size_t)LAYERS * HD * HD;        // 4x[512,256] KC=32
    short* mw2_t = mw1_t + (size_t)LAYERS * HD * 2 * HD;   // 4x[256,512] KC=64
    short* wo_t  = mw2_t + (size_t)LAYERS * 2 * HD * HD;   // [256,256] KC=32
    float* cbias = (float*)(wo_t + (size_t)HD * OUTDIM);   // 4x[1024] fp32

    const int T = 256;
    const int nNH = NNODES * NHEADS;

    // ---- merged prep (zeros + all weight converts) ----
    prep_kernel<<<(PREP_TOTAL + T - 1) / T, T, 0, stream>>>(
        x0, wi, inw, wg, inb, ow, mw1, mw2, wo,
        x016, wi_t, wcomb, cbias, ow_c, mw1_t, mw2_t, wo_t, cnt, fill);

    // ---- CSR build ----
    hist_kernel<<<(NEDGES + T - 1) / T, T, 0, stream>>>(dstI, cnt);
    scan_kernel<<<1, 256, 0, stream>>>(cnt, row_ptr);
    scatter_kernel<<<(NEDGES + T - 1) / T, T, 0, stream>>>(srcI, dstI, row_ptr, fill, srcs);

    // x = relu(x0 @ wi + bi) -> xcur fp32 + xcur16 bf16(blocked)
    gemm_mfma_kernel<64><<<dim3(HD / 64, NNODES / GBM), 256, 0, stream>>>(
        x016, wi_t, bi, nullptr, xcur, xcur16, NNODES, HD, IND, 1);

    for (int i = 0; i < LAYERS; i++) {
        const float* asrc_i = asrc + (size_t)i * NHEADS * OCD;
        const float* adst_i = adst + (size_t)i * NHEADS * OCD;
        const float* bg_i   = bg + (size_t)i * HD;
        const float* g1_i   = g1 + (size_t)i * HD;
        const float* b1_i   = b1 + (size_t)i * HD;
        const float* ob_i   = ob + (size_t)i * HD;
        const float* g2_i   = g2 + (size_t)i * HD;
        const float* b2_i   = b2 + (size_t)i * HD;
        const float* mb1_i  = mb1 + (size_t)i * 2 * HD;
        const float* mb2_i  = mb2 + (size_t)i * HD;
        const float* g3_i   = g3 + (size_t)i * HD;
        const float* b3_i   = b3 + (size_t)i * HD;
        const short* wcomb_i = wcomb + (size_t)i * 1024 * HD;
        const float* cbias_i = cbias + (size_t)i * 1024;
        const short* ow_ci  = ow_c + (size_t)i * HD * HD;
        const short* mw1_ti = mw1_t + (size_t)i * HD * 2 * HD;
        const short* mw2_ti = mw2_t + (size_t)i * 2 * HD * HD;

        // ---- fused qkv+wg projection: [N,1024] = xcur16 @ [qkv|wg] ----
        gemm_mfma_kernel<128><<<dim3(1024 / 128, NNODES / GBM), 256, 0, stream>>>(
            xcur16, wcomb_i, cbias_i, nullptr, nullptr, xq16, NNODES, 1024, HD, 0);

        // ---- GAT local branch ----
        gat_scores_kernel<<<(nNH + T - 1) / T, T, 0, stream>>>(xq16, asrc_i, adst_i, ssrc, sdst);
        gat_agg_ln_kernel<<<NNODES / 4, 256, 0, stream>>>(
            row_ptr, srcs, ssrc, sdst, xq16, xcur, bg_i, g1_i, b1_i, hbuf);

        // ---- global MHA branch (all-MFMA) ----
        mha_mfma_kernel<<<dim3(NGRAPH, NHEADS), 256, 0, stream>>>(xq16, b16a);
        // fused: obuf/b16a = LN(mha@ow + ob + xcur)*g2+b2 + hbuf
        gemm_ln_kernel<<<dim3(1, NNODES / 64), 256, 0, stream>>>(
            b16a, ow_ci, ob_i, xcur, g2_i, b2_i, hbuf, obuf, b16a, HD);

        // ---- MLP ----
        gemm_mfma_kernel<128><<<dim3(2 * HD / 128, NNODES / GBM), 256, 0, stream>>>(
            b16a, mw1_ti, mb1_i, nullptr, nullptr, hid16, NNODES, 2 * HD, HD, 1);
        // fused: xcur/xcur16 = LN(hid@mw2 + mb2 + obuf)*g3+b3
        gemm_ln_kernel<<<dim3(1, NNODES / 64), 256, 0, stream>>>(
            hid16, mw2_ti, mb2_i, obuf, g3_i, b3_i, nullptr, xcur, xcur16, 2 * HD);
    }

    // final LN + output projection -> d_out (fp32)
    ln4_kernel<<<NNODES / 4, 256, 0, stream>>>(xcur, nullptr, gf, bf_, nullptr, nullptr, b16a);
    gemm_mfma_kernel<64><<<dim3(OUTDIM / 64, NNODES / GBM), 256, 0, stream>>>(
        b16a, wo_t, bo, nullptr, (float*)d_out, nullptr, NNODES, OUTDIM, HD, 0);
}

// Round 15
// 749.442 us; speedup vs baseline: 1.3381x; 1.3381x over previous
//
#include <hip/hip_runtime.h>
#include <hip/hip_bf16.h>

#define NNODES 16384
#define NEDGES 262144
#define IND    128
#define HD     256
#define OUTDIM 256
#define LAYERS 4
#define NHEADS 8
#define OCD    32
#define NGRAPH 64
#define NBATCH 256
#define XQSTR  1024   // xq16 row stride (row-major: gather/mha consumers)

typedef __hip_bfloat16 bf16;
typedef __attribute__((ext_vector_type(8))) short bf16x8;
typedef __attribute__((ext_vector_type(4))) short s16x4;
typedef __attribute__((ext_vector_type(4))) float f32x4;

__device__ __forceinline__ short bfbits(float v) {
    bf16 h = __float2bfloat16(v);
    return *(short*)&h;
}
__device__ __forceinline__ float b2f(short s) {
    return __uint_as_float(((unsigned)(unsigned short)s) << 16);
}

// blocked bf16 layout (GEMM A/B operands ONLY): X[(r/64)*KC + c/8][r%64][c%8].
// Coalesced 1 KB DMA per wave AND conflict-free ds_read_b128 fragments.
__device__ __forceinline__ size_t bidx(int row, int col, int KC) {
    return ((size_t)((row >> 6) * KC + (col >> 3)) << 9) + ((row & 63) << 3) + (col & 7);
}

// direct global->LDS DMA, 16 B/lane; lds base wave-uniform
__device__ __forceinline__ void gload_lds16(const short* g, short* l) {
    __builtin_amdgcn_global_load_lds(
        (const __attribute__((address_space(1))) void*)g,
        (__attribute__((address_space(3))) void*)l, 16, 0, 0);
}

// ---------------- merged prep: zeros + all weight converts (blocked layout) ----
#define PREP_TOTAL (32768 + NNODES*IND + IND*HD + LAYERS*1024*HD + LAYERS*1024 \
                    + LAYERS*HD*HD + LAYERS*HD*2*HD + LAYERS*2*HD*HD + HD*OUTDIM)
__global__ void prep_kernel(const float* __restrict__ x0, const float* __restrict__ wi,
                            const float* __restrict__ inw, const float* __restrict__ wg,
                            const float* __restrict__ inb, const float* __restrict__ ow,
                            const float* __restrict__ mw1, const float* __restrict__ mw2,
                            const float* __restrict__ wo,
                            short* __restrict__ x016, short* __restrict__ wi_t,
                            short* __restrict__ wcomb, float* __restrict__ cbias,
                            short* __restrict__ ow_c, short* __restrict__ mw1_t,
                            short* __restrict__ mw2_t, short* __restrict__ wo_t,
                            int* __restrict__ cnt, int* __restrict__ fill)
{
    int i = blockIdx.x * blockDim.x + threadIdx.x;
    if (i < 32768) {
        if (i < NNODES) cnt[i] = 0; else fill[i - NNODES] = 0;
        return;
    }
    i -= 32768;
    if (i < NNODES * IND) {                // x0 -> blocked [N,128], KC=16
        int row = i / IND, col = i % IND;
        x016[bidx(row, col, 16)] = bfbits(x0[i]);
        return;
    }
    i -= NNODES * IND;
    if (i < IND * HD) {                    // wi [128,256] -> B[n=256][k=128], KC=16
        int k = i / HD, n = i % HD;
        wi_t[bidx(n, k, 16)] = bfbits(wi[i]);
        return;
    }
    i -= IND * HD;
    if (i < LAYERS * 1024 * HD) {          // wcomb rows 0..767=inw, 768..1023=wg^T, KC=32
        int l = i >> 18, r = (i >> 8) & 1023, k = i & 255;
        float v = (r < 768) ? inw[(size_t)l * 768 * 256 + r * 256 + k]
                            : wg[(size_t)l * 256 * 256 + k * 256 + (r - 768)];
        wcomb[((size_t)l << 18) + bidx(r, k, 32)] = bfbits(v);
        return;
    }
    i -= LAYERS * 1024 * HD;
    if (i < LAYERS * 1024) {               // cbias (fp32)
        int l = i >> 10, c = i & 1023;
        cbias[i] = (c < 768) ? inb[l * 768 + c] : 0.f;
        return;
    }
    i -= LAYERS * 1024;
    if (i < LAYERS * HD * HD) {            // ow: B[r=256][k=256], KC=32
        int l = i >> 16, rem = i & 65535, r = rem >> 8, k = rem & 255;
        ow_c[((size_t)l << 16) + bidx(r, k, 32)] = bfbits(ow[i]);
        return;
    }
    i -= LAYERS * HD * HD;
    if (i < LAYERS * HD * 2 * HD) {        // mw1 [k=256][n=512] -> B[n][k], KC=32
        int l = i / (HD * 2 * HD), rem = i % (HD * 2 * HD);
        int k = rem / (2 * HD), n = rem % (2 * HD);
        mw1_t[(size_t)l * HD * 2 * HD + bidx(n, k, 32)] = bfbits(mw1[i]);
        return;
    }
    i -= LAYERS * HD * 2 * HD;
    if (i < LAYERS * 2 * HD * HD) {        // mw2 [k=512][n=256] -> B[n][k], KC=64
        int l = i / (2 * HD * HD), rem = i % (2 * HD * HD);
        int k = rem / HD, n = rem % HD;
        mw2_t[(size_t)l * 2 * HD * HD + bidx(n, k, 64)] = bfbits(mw2[i]);
        return;
    }
    i -= LAYERS * 2 * HD * HD;
    if (i < HD * OUTDIM) {                 // wo [k=256][n=256] -> B[n][k], KC=32
        int k = i / OUTDIM, n = i % OUTDIM;
        wo_t[bidx(n, k, 32)] = bfbits(wo[i]);
    }
}

// ---------------- CSR build ----------------------------------------------------
__global__ void hist_kernel(const int* __restrict__ dst, int* __restrict__ cnt)
{
    int e = blockIdx.x * blockDim.x + threadIdx.x;
    if (e < NEDGES) atomicAdd(&cnt[dst[e]], 1);
}

__global__ void scan_kernel(const int* __restrict__ cnt, int* __restrict__ row_ptr)
{
    __shared__ int part[256];
    int t = threadIdx.x;
    const int PER = NNODES / 256;
    int base = t * PER;
    int s = 0;
    for (int i = 0; i < PER; i++) s += cnt[base + i];
    part[t] = s;
    __syncthreads();
    for (int off = 1; off < 256; off <<= 1) {
        int v = (t >= off) ? part[t - off] : 0;
        __syncthreads();
        part[t] += v;
        __syncthreads();
    }
    int run = (t == 0) ? 0 : part[t - 1];
    for (int i = 0; i < PER; i++) { row_ptr[base + i] = run; run += cnt[base + i]; }
    if (t == 255) row_ptr[NNODES] = run;
}

__global__ void scatter_kernel(const int* __restrict__ src, const int* __restrict__ dst,
                               const int* __restrict__ row_ptr, int* __restrict__ fill,
                               int* __restrict__ srcs)
{
    int e = blockIdx.x * blockDim.x + threadIdx.x;
    if (e >= NEDGES) return;
    int d = dst[e];
    int pos = row_ptr[d] + atomicAdd(&fill[d], 1);
    srcs[pos] = src[e];
}

// ---------------- GAT per-node attention scores (row-major xw16) ---------------
__global__ void gat_scores_kernel(const short* __restrict__ xw16,
                                  const float* __restrict__ asrc, const float* __restrict__ adst,
                                  float* __restrict__ ssrc, float* __restrict__ sdst)
{
    int i = blockIdx.x * blockDim.x + threadIdx.x;   // n*NHEADS + h
    if (i >= NNODES * NHEADS) return;
    int n = i >> 3, h = i & 7;
    const bf16x8* xr = (const bf16x8*)(xw16 + (size_t)n * XQSTR + h * OCD);
    float s1 = 0.f, s2 = 0.f;
#pragma unroll
    for (int g = 0; g < 4; g++) {
        bf16x8 v8 = xr[g];
#pragma unroll
        for (int j = 0; j < 8; j++) {
            float v = b2f(v8[j]);
            int d = g * 8 + j;
            s1 += v * asrc[h * OCD + d];
            s2 += v * adst[h * OCD + d];
        }
    }
    ssrc[i] = s1;
    sdst[i] = s2;
}

// ---------------- fused GAT softmax + aggregation + LayerNorm ------------------
// Wave-per-node, row-major 8 B gathers (512 B/row locality), shuffle LN.
__global__ __launch_bounds__(256)
void gat_agg_ln_kernel(const int* __restrict__ row_ptr, const int* __restrict__ srcs,
                       const float* __restrict__ ssrc, const float* __restrict__ sdst,
                       const short* __restrict__ xw16, const float* __restrict__ xcur,
                       const float* __restrict__ colbias, const float* __restrict__ gamma,
                       const float* __restrict__ beta, float* __restrict__ out)
{
    int wave = threadIdx.x >> 6, lane = threadIdx.x & 63;
    int n = blockIdx.x * 4 + wave;
    int c0 = lane << 2;            // 4 channels per lane
    int h = c0 >> 5;               // head of all 4 channels
    int start = row_ptr[n];
    int deg = row_ptr[n + 1] - start;
    float sd = sdst[n * NHEADS + h];

    float ax = 0.f, ay = 0.f, az = 0.f, aw = 0.f, l = 0.f;
    int j = 0;
    for (; j + 4 <= deg; j += 4) {
        int e0 = srcs[start + j + 0], e1 = srcs[start + j + 1];
        int e2 = srcs[start + j + 2], e3 = srcs[start + j + 3];
        s16x4 r0 = *(const s16x4*)&xw16[(size_t)e0 * XQSTR + c0];
        s16x4 r1 = *(const s16x4*)&xw16[(size_t)e1 * XQSTR + c0];
        s16x4 r2 = *(const s16x4*)&xw16[(size_t)e2 * XQSTR + c0];
        s16x4 r3 = *(const s16x4*)&xw16[(size_t)e3 * XQSTR + c0];
        float a0 = ssrc[e0 * NHEADS + h] + sd; a0 = a0 > 0.f ? a0 : 0.2f * a0;
        float a1 = ssrc[e1 * NHEADS + h] + sd; a1 = a1 > 0.f ? a1 : 0.2f * a1;
        float a2 = ssrc[e2 * NHEADS + h] + sd; a2 = a2 > 0.f ? a2 : 0.2f * a2;
        float a3 = ssrc[e3 * NHEADS + h] + sd; a3 = a3 > 0.f ? a3 : 0.2f * a3;
        float p0 = __expf(a0), p1 = __expf(a1), p2 = __expf(a2), p3 = __expf(a3);
        l += (p0 + p1) + (p2 + p3);
        ax += p0 * b2f(r0[0]) + p1 * b2f(r1[0]) + p2 * b2f(r2[0]) + p3 * b2f(r3[0]);
        ay += p0 * b2f(r0[1]) + p1 * b2f(r1[1]) + p2 * b2f(r2[1]) + p3 * b2f(r3[1]);
        az += p0 * b2f(r0[2]) + p1 * b2f(r1[2]) + p2 * b2f(r2[2]) + p3 * b2f(r3[2]);
        aw += p0 * b2f(r0[3]) + p1 * b2f(r1[3]) + p2 * b2f(r2[3]) + p3 * b2f(r3[3]);
    }
    for (; j < deg; j++) {
        int e0 = srcs[start + j];
        s16x4 r0 = *(const s16x4*)&xw16[(size_t)e0 * XQSTR + c0];
        float a0 = ssrc[e0 * NHEADS + h] + sd; a0 = a0 > 0.f ? a0 : 0.2f * a0;
        float p0 = __expf(a0);
        l += p0;
        ax += p0 * b2f(r0[0]); ay += p0 * b2f(r0[1]);
        az += p0 * b2f(r0[2]); aw += p0 * b2f(r0[3]);
    }
    float invl = deg ? 1.f / l : 0.f;
    size_t base = (size_t)n * HD + c0;
    float4 x4 = *(const float4*)&xcur[base];
    float4 cb = *(const float4*)&colbias[c0];
    float4 v;
    v.x = ax * invl + x4.x + cb.x;
    v.y = ay * invl + x4.y + cb.y;
    v.z = az * invl + x4.z + cb.z;
    v.w = aw * invl + x4.w + cb.w;
    float s = v.x + v.y + v.z + v.w;
    float q = v.x * v.x + v.y * v.y + v.z * v.z + v.w * v.w;
#pragma unroll
    for (int off = 1; off < 64; off <<= 1) {
        s += __shfl_xor(s, off);
        q += __shfl_xor(q, off);
    }
    float mean = s * (1.f / HD);
    float var  = fmaxf(q * (1.f / HD) - mean * mean, 0.f);
    float inv  = rsqrtf(var + 1e-5f);
    float4 g  = *(const float4*)&gamma[c0];
    float4 bt = *(const float4*)&beta[c0];
    float4 y;
    y.x = (v.x - mean) * inv * g.x + bt.x;
    y.y = (v.y - mean) * inv * g.y + bt.y;
    y.z = (v.z - mean) * inv * g.z + bt.z;
    y.w = (v.w - mean) * inv * g.w + bt.w;
    *(float4*)&out[base] = y;
}

// ---------------- bf16 MFMA GEMM (blocked A/B inputs) --------------------------
// Coalesced 1 KB DMA/wave + conflict-free LDS reads. Swapped-operand mfma ->
// vectorized epilogue. C16 layout: row-major (c16rm=1, stride Nc) or blocked.
#define GBM 128
#define GBK 32

template<int TN>
__global__ __launch_bounds__(256)
void gemm_mfma_kernel(const short* __restrict__ A16, const short* __restrict__ B16,
                      const float* __restrict__ bias, const float* __restrict__ resid,
                      float* __restrict__ Cf, short* __restrict__ C16,
                      int M, int Nc, int K, int relu, int c16rm)
{
    constexpr int NTF = TN / 32;          // n-frags per wave
    __shared__ short As[GBM * GBK];       // 512 slots
    __shared__ short Bs[TN * GBK];
    int tid = threadIdx.x;
    int wid = tid >> 6, lane = tid & 63;
    int quad = lane >> 4, l16 = lane & 15;
    int wm = wid >> 1, wn = wid & 1;
    int rowBase = blockIdx.y * GBM;
    int colBase = blockIdx.x * TN;
    int KC = K >> 3;

    f32x4 acc[4][NTF];
#pragma unroll
    for (int mt = 0; mt < 4; mt++)
#pragma unroll
        for (int nt = 0; nt < NTF; nt++) acc[mt][nt] = (f32x4)(0.f);

    const short* Ag0 = A16 + (((size_t)(blockIdx.y * 2 + 0) * KC + wid) << 9) + lane * 8;
    const short* Ag1 = A16 + (((size_t)(blockIdx.y * 2 + 1) * KC + wid) << 9) + lane * 8;
    const short* Bg0 = B16 + (((size_t)((colBase >> 6) + 0) * KC + wid) << 9) + lane * 8;
    const short* Bg1 = (TN == 128) ?
        B16 + (((size_t)((colBase >> 6) + 1) * KC + wid) << 9) + lane * 8 : nullptr;
    short* AsD0 = As + (wid * 128 + 0) * 8;
    short* AsD1 = As + (wid * 128 + 64) * 8;
    short* BsD0 = Bs + (wid * TN) * 8;
    short* BsD1 = Bs + (wid * TN + 64) * 8;

    for (int t = 0; t < (K >> 5); t++) {
        gload_lds16(Ag0 + t * 2048, AsD0);
        gload_lds16(Ag1 + t * 2048, AsD1);
        gload_lds16(Bg0 + t * 2048, BsD0);
        if (TN == 128) gload_lds16(Bg1 + t * 2048, BsD1);
        __syncthreads();
        bf16x8 aF[4], bF[NTF];
#pragma unroll
        for (int mt = 0; mt < 4; mt++)
            aF[mt] = *(bf16x8*)&As[(quad * 128 + wm * 64 + mt * 16 + l16) * 8];
#pragma unroll
        for (int nt = 0; nt < NTF; nt++)
            bF[nt] = *(bf16x8*)&Bs[(quad * TN + wn * (TN / 2) + nt * 16 + l16) * 8];
#pragma unroll
        for (int mt = 0; mt < 4; mt++)
#pragma unroll
            for (int nt = 0; nt < NTF; nt++)
                acc[mt][nt] = __builtin_amdgcn_mfma_f32_16x16x32_bf16(
                    bF[nt], aF[mt], acc[mt][nt], 0, 0, 0);   // swapped operands
        __syncthreads();
    }

#pragma unroll
    for (int mt = 0; mt < 4; mt++) {
        int row = rowBase + wm * 64 + mt * 16 + l16;
#pragma unroll
        for (int nt = 0; nt < NTF; nt++) {
            int col0 = colBase + wn * (TN / 2) + nt * 16 + quad * 4;
            f32x4 v = acc[mt][nt];
            if (bias) {
                float4 b4 = *(const float4*)&bias[col0];
                v[0] += b4.x; v[1] += b4.y; v[2] += b4.z; v[3] += b4.w;
            }
            if (resid) {
                float4 r4 = *(const float4*)&resid[(size_t)row * Nc + col0];
                v[0] += r4.x; v[1] += r4.y; v[2] += r4.z; v[3] += r4.w;
            }
            if (relu) {
                v[0] = fmaxf(v[0], 0.f); v[1] = fmaxf(v[1], 0.f);
                v[2] = fmaxf(v[2], 0.f); v[3] = fmaxf(v[3], 0.f);
            }
            if (Cf) {
                float4 o; o.x = v[0]; o.y = v[1]; o.z = v[2]; o.w = v[3];
                *(float4*)&Cf[(size_t)row * Nc + col0] = o;
            }
            if (C16) {
                s16x4 o;
                o[0] = bfbits(v[0]); o[1] = bfbits(v[1]);
                o[2] = bfbits(v[2]); o[3] = bfbits(v[3]);
                if (c16rm) *(s16x4*)&C16[(size_t)row * Nc + col0] = o;
                else       *(s16x4*)&C16[bidx(row, col0, Nc >> 3)] = o;
            }
        }
    }
}

// ---------------- fused GEMM + residual + LayerNorm (+postadd) -----------------
// 64x256 tile; blocked A/B; out16 blocked (A-operand consumer); 2-shuffle LN.
__global__ __launch_bounds__(256)
void gemm_ln_kernel(const short* __restrict__ A16, const short* __restrict__ B16,
                    const float* __restrict__ bias, const float* __restrict__ resid,
                    const float* __restrict__ gamma, const float* __restrict__ beta,
                    const float* __restrict__ postadd,
                    float* __restrict__ outf, short* __restrict__ out16, int K)
{
    __shared__ short As[64 * GBK];        // 256 slots
    __shared__ short Bs[256 * GBK];       // 1024 slots
    int tid = threadIdx.x;
    int wid = tid >> 6, lane = tid & 63;
    int quad = lane >> 4, l16 = lane & 15;
    int rowBase = blockIdx.y * 64;
    int KC = K >> 3;

    f32x4 acc[16];
#pragma unroll
    for (int nt = 0; nt < 16; nt++) acc[nt] = (f32x4)(0.f);

    const short* Ag  = A16 + (((size_t)blockIdx.y * KC + wid) << 9) + lane * 8;
    const short* Bg0 = B16 + (((size_t)0 * KC + wid) << 9) + lane * 8;
    const short* Bg1 = B16 + (((size_t)1 * KC + wid) << 9) + lane * 8;
    const short* Bg2 = B16 + (((size_t)2 * KC + wid) << 9) + lane * 8;
    const short* Bg3 = B16 + (((size_t)3 * KC + wid) << 9) + lane * 8;
    short* AsD  = As + (wid * 64) * 8;
    short* BsD0 = Bs + (wid * 256 + 0) * 8;
    short* BsD1 = Bs + (wid * 256 + 64) * 8;
    short* BsD2 = Bs + (wid * 256 + 128) * 8;
    short* BsD3 = Bs + (wid * 256 + 192) * 8;

    for (int t = 0; t < (K >> 5); t++) {
        gload_lds16(Ag + t * 2048, AsD);
        gload_lds16(Bg0 + t * 2048, BsD0);
        gload_lds16(Bg1 + t * 2048, BsD1);
        gload_lds16(Bg2 + t * 2048, BsD2);
        gload_lds16(Bg3 + t * 2048, BsD3);
        __syncthreads();
        bf16x8 aF = *(bf16x8*)&As[(quad * 64 + wid * 16 + l16) * 8];
#pragma unroll
        for (int nt = 0; nt < 16; nt++) {
            bf16x8 bF = *(bf16x8*)&Bs[(quad * 256 + nt * 16 + l16) * 8];
            acc[nt] = __builtin_amdgcn_mfma_f32_16x16x32_bf16(bF, aF, acc[nt], 0, 0, 0);
        }
        __syncthreads();
    }

    int row = rowBase + wid * 16 + l16;
    float s = 0.f, q = 0.f;
#pragma unroll
    for (int nt = 0; nt < 16; nt++) {
        int col0 = nt * 16 + quad * 4;
        f32x4 v = acc[nt];
        float4 b4 = *(const float4*)&bias[col0];
        float4 r4 = *(const float4*)&resid[(size_t)row * HD + col0];
        v[0] += b4.x + r4.x; v[1] += b4.y + r4.y;
        v[2] += b4.z + r4.z; v[3] += b4.w + r4.w;
        acc[nt] = v;
        s += (v[0] + v[1]) + (v[2] + v[3]);
        q += (v[0] * v[0] + v[1] * v[1]) + (v[2] * v[2] + v[3] * v[3]);
    }
    s += __shfl_xor(s, 16); s += __shfl_xor(s, 32);
    q += __shfl_xor(q, 16); q += __shfl_xor(q, 32);
    float mean = s * (1.f / HD);
    float var  = fmaxf(q * (1.f / HD) - mean * mean, 0.f);
    float inv  = rsqrtf(var + 1e-5f);
#pragma unroll
    for (int nt = 0; nt < 16; nt++) {
        int col0 = nt * 16 + quad * 4;
        f32x4 v = acc[nt];
        float4 g4 = *(const float4*)&gamma[col0];
        float4 bt = *(const float4*)&beta[col0];
        float4 y;
        y.x = (v[0] - mean) * inv * g4.x + bt.x;
        y.y = (v[1] - mean) * inv * g4.y + bt.y;
        y.z = (v[2] - mean) * inv * g4.z + bt.z;
        y.w = (v[3] - mean) * inv * g4.w + bt.w;
        if (postadd) {
            float4 p4 = *(const float4*)&postadd[(size_t)row * HD + col0];
            y.x += p4.x; y.y += p4.y; y.z += p4.z; y.w += p4.w;
        }
        *(float4*)&outf[(size_t)row * HD + col0] = y;
        s16x4 o;
        o[0] = bfbits(y.x); o[1] = bfbits(y.y); o[2] = bfbits(y.z); o[3] = bfbits(y.w);
        *(s16x4*)&out16[bidx(row, col0, 32)] = o;
    }
}

// ---------------- LayerNorm: wave-per-row, float4, shuffle-only ----------------
__global__ __launch_bounds__(256)
void ln4_kernel(const float* __restrict__ in, const float* __restrict__ res,
                const float* __restrict__ gamma, const float* __restrict__ beta,
                const float* __restrict__ postadd,
                float* __restrict__ outf, short* __restrict__ out16)
{
    int wave = threadIdx.x >> 6, lane = threadIdx.x & 63;
    int row = blockIdx.x * 4 + wave;
    size_t base = (size_t)row * HD + lane * 4;
    float4 v = *(const float4*)&in[base];
    if (res) {
        float4 r = *(const float4*)&res[base];
        v.x += r.x; v.y += r.y; v.z += r.z; v.w += r.w;
    }
    float s = v.x + v.y + v.z + v.w;
    float q = v.x * v.x + v.y * v.y + v.z * v.z + v.w * v.w;
#pragma unroll
    for (int off = 1; off < 64; off <<= 1) {
        s += __shfl_xor(s, off);
        q += __shfl_xor(q, off);
    }
    float mean = s * (1.f / HD);
    float var  = fmaxf(q * (1.f / HD) - mean * mean, 0.f);
    float inv  = rsqrtf(var + 1e-5f);
    float4 g  = *(const float4*)&gamma[lane * 4];
    float4 bt = *(const float4*)&beta[lane * 4];
    float4 y;
    y.x = (v.x - mean) * inv * g.x + bt.x;
    y.y = (v.y - mean) * inv * g.y + bt.y;
    y.z = (v.z - mean) * inv * g.z + bt.z;
    y.w = (v.w - mean) * inv * g.w + bt.w;
    if (postadd) {
        float4 p = *(const float4*)&postadd[base];
        y.x += p.x; y.y += p.y; y.z += p.z; y.w += p.w;
    }
    if (outf) *(float4*)&outf[base] = y;
    if (out16) {
        s16x4 o;
        o[0] = bfbits(y.x); o[1] = bfbits(y.y); o[2] = bfbits(y.z); o[3] = bfbits(y.w);
        *(s16x4*)&out16[bidx(row, lane * 4, 32)] = o;
    }
}

// ---------------- MFMA per-graph MHA (row-major qkv16, stride XQSTR) -----------
#define PSTR 72                       // slot stride 9 (x16B) == 1 mod 8 -> conflict-free
__global__ __launch_bounds__(256)
void mha_mfma_kernel(const short* __restrict__ qkv16, short* __restrict__ o16)
{
    __shared__ short smem[4 * 64 * PSTR + 32 * PSTR];   // P + V^T
    short* VT = smem + 4 * 64 * PSTR;

    int b = blockIdx.x, h = blockIdx.y;
    int tid = threadIdx.x;
    int wid = tid >> 6, lane = tid & 63;
    int quad = lane >> 4, l16 = lane & 15;
    int base = b * NBATCH;
    int qrow0 = wid * 64;
    short* Pme = smem + wid * 64 * PSTR;

    const float scale2 = 0.17677669529663687f * 1.4426950408889634f; // 1/sqrt(32)*log2(e)

    bf16x8 qA[4];
#pragma unroll
    for (int mt = 0; mt < 4; mt++)
        qA[mt] = *(const bf16x8*)&qkv16[(size_t)(base + qrow0 + mt * 16 + l16) * XQSTR + h * 32 + quad * 8];

    f32x4 accO[4][2];
#pragma unroll
    for (int mt = 0; mt < 4; mt++)
#pragma unroll
        for (int dt = 0; dt < 2; dt++) accO[mt][dt] = (f32x4)(0.f);
    float lsum[4][4];
#pragma unroll
    for (int mt = 0; mt < 4; mt++)
#pragma unroll
        for (int r = 0; r < 4; r++) lsum[mt][r] = 0.f;

    for (int c = 0; c < 4; c++) {                  // 4 key-chunks of 64
        __syncthreads();
        {
            int key = tid >> 2, dq = (tid & 3) * 8;
            bf16x8 v = *(const bf16x8*)&qkv16[(size_t)(base + c * 64 + key) * XQSTR + 512 + h * 32 + dq];
#pragma unroll
            for (int j = 0; j < 8; j++) VT[(dq + j) * PSTR + key] = v[j];
        }
        __syncthreads();
        bf16x8 kB[4];
#pragma unroll
        for (int kt = 0; kt < 4; kt++)
            kB[kt] = *(const bf16x8*)&qkv16[(size_t)(base + c * 64 + kt * 16 + l16) * XQSTR + 256 + h * 32 + quad * 8];
#pragma unroll
        for (int mt = 0; mt < 4; mt++) {
#pragma unroll
            for (int kt = 0; kt < 4; kt++) {
                f32x4 s = __builtin_amdgcn_mfma_f32_16x16x32_bf16(qA[mt], kB[kt], (f32x4)(0.f), 0, 0, 0);
#pragma unroll
                for (int r = 0; r < 4; r++) {
                    float p = exp2f(s[r] * scale2);
                    lsum[mt][r] += p;
                    Pme[(mt * 16 + quad * 4 + r) * PSTR + kt * 16 + l16] = bfbits(p);
                }
            }
        }
        __syncthreads();
#pragma unroll
        for (int mt = 0; mt < 4; mt++) {
#pragma unroll
            for (int ks = 0; ks < 2; ks++) {
                bf16x8 pA = *(bf16x8*)&Pme[(mt * 16 + l16) * PSTR + ks * 32 + quad * 8];
#pragma unroll
                for (int dt = 0; dt < 2; dt++) {
                    bf16x8 vB = *(bf16x8*)&VT[(dt * 16 + l16) * PSTR + ks * 32 + quad * 8];
                    accO[mt][dt] = __builtin_amdgcn_mfma_f32_16x16x32_bf16(pA, vB, accO[mt][dt], 0, 0, 0);
                }
            }
        }
    }
#pragma unroll
    for (int mt = 0; mt < 4; mt++)
#pragma unroll
        for (int r = 0; r < 4; r++) {
            float v = lsum[mt][r];
            v += __shfl_xor(v, 1);
            v += __shfl_xor(v, 2);
            v += __shfl_xor(v, 4);
            v += __shfl_xor(v, 8);
            lsum[mt][r] = v;
        }
    // o16 (b16a) is a GEMM A-operand consumer -> blocked write
#pragma unroll
    for (int mt = 0; mt < 4; mt++)
#pragma unroll
        for (int dt = 0; dt < 2; dt++)
#pragma unroll
            for (int r = 0; r < 4; r++) {
                int row = base + qrow0 + mt * 16 + quad * 4 + r;
                int col = h * 32 + dt * 16 + l16;
                o16[bidx(row, col, 32)] = bfbits(accO[mt][dt][r] / lsum[mt][r]);
            }
}

// ------------------------------------------------------------------------------
extern "C" void kernel_launch(void* const* d_in, const int* in_sizes, int n_in,
                              void* d_out, int out_size, void* d_ws, size_t ws_size,
                              hipStream_t stream)
{
    const float* x0   = (const float*)d_in[0];
    const int*   ei   = (const int*)d_in[1];
    const float* wi   = (const float*)d_in[2];
    const float* bi   = (const float*)d_in[3];
    const float* wg   = (const float*)d_in[4];
    const float* asrc = (const float*)d_in[5];
    const float* adst = (const float*)d_in[6];
    const float* bg   = (const float*)d_in[7];
    const float* g1   = (const float*)d_in[8];
    const float* b1   = (const float*)d_in[9];
    const float* inw  = (const float*)d_in[10];
    const float* inb  = (const float*)d_in[11];
    const float* ow   = (const float*)d_in[12];
    const float* ob   = (const float*)d_in[13];
    const float* g2   = (const float*)d_in[14];
    const float* b2   = (const float*)d_in[15];
    const float* mw1  = (const float*)d_in[16];
    const float* mb1  = (const float*)d_in[17];
    const float* mw2  = (const float*)d_in[18];
    const float* mb2  = (const float*)d_in[19];
    const float* g3   = (const float*)d_in[20];
    const float* b3   = (const float*)d_in[21];
    const float* gf   = (const float*)d_in[22];
    const float* bf_  = (const float*)d_in[23];
    const float* wo   = (const float*)d_in[24];
    const float* bo   = (const float*)d_in[25];

    const int* srcI = ei;
    const int* dstI = ei + NEDGES;

    // ---- workspace layout ----
    const size_t NH = (size_t)NNODES * HD;           // 4,194,304
    float* ws   = (float*)d_ws;
    float* xcur = ws;                // [N,H] fp32
    float* xw   = xcur + NH;         // [N,H] fp32 (layout stability)
    float* hbuf = xw + NH;           // [N,H] fp32
    float* obuf = hbuf + NH;         // [N,H] fp32
    float* qkvb = obuf + NH;         // bf16 [N,1024] ROW-MAJOR (gather/mha)
    int*   srcs    = (int*)(qkvb + 3 * NH);          // [E]
    int*   row_ptr = srcs + NEDGES;                  // [N+1]
    int*   cnt     = row_ptr + NNODES + 1;           // [N]
    int*   fill    = cnt + NNODES;                   // [N]
    float* ssrc    = (float*)(fill + NNODES);        // [N,8]
    float* sdst    = ssrc + (size_t)NNODES * NHEADS; // [N,8]
    // bf16 (short) region — GEMM A-operands + weights BLOCKED; xq16 row-major
    short* xq16   = (short*)qkvb;                    // [N,1024] row-major
    short* x016   = (short*)(sdst + (size_t)NNODES * NHEADS);  // [N,128] blocked KC=16
    short* xcur16 = x016 + (size_t)NNODES * IND;     // [N,H] blocked KC=32
    short* b16a   = xcur16 + NH;                     // [N,H] blocked KC=32
    short* hid16  = b16a + NH;                       // [N,2H] blocked KC=64
    // bf16 weights (blocked)
    short* wi_t  = hid16 + 2 * NH;                         // [256,128] KC=16
    short* wcomb = wi_t + (size_t)HD * IND;                // 4x[1024,256] KC=32
    short* ow_c  = wcomb + (size_t)LAYERS * 1024 * HD;     // 4x[256,256] KC=32
    short* mw1_t = ow_c + (size_t)LAYERS * HD * HD;        // 4x[512,256] KC=32
    short* mw2_t = mw1_t + (size_t)LAYERS * HD * 2 * HD;   // 4x[256,512] KC=64
    short* wo_t  = mw2_t + (size_t)LAYERS * 2 * HD * HD;   // [256,256] KC=32
    float* cbias = (float*)(wo_t + (size_t)HD * OUTDIM);   // 4x[1024] fp32

    const int T = 256;
    const int nNH = NNODES * NHEADS;

    // ---- merged prep (zeros + all weight converts) ----
    prep_kernel<<<(PREP_TOTAL + T - 1) / T, T, 0, stream>>>(
        x0, wi, inw, wg, inb, ow, mw1, mw2, wo,
        x016, wi_t, wcomb, cbias, ow_c, mw1_t, mw2_t, wo_t, cnt, fill);

    // ---- CSR build ----
    hist_kernel<<<(NEDGES + T - 1) / T, T, 0, stream>>>(dstI, cnt);
    scan_kernel<<<1, 256, 0, stream>>>(cnt, row_ptr);
    scatter_kernel<<<(NEDGES + T - 1) / T, T, 0, stream>>>(srcI, dstI, row_ptr, fill, srcs);

    // x = relu(x0 @ wi + bi) -> xcur fp32 + xcur16 bf16(blocked)
    gemm_mfma_kernel<64><<<dim3(HD / 64, NNODES / GBM), 256, 0, stream>>>(
        x016, wi_t, bi, nullptr, xcur, xcur16, NNODES, HD, IND, 1, 0);

    for (int i = 0; i < LAYERS; i++) {
        const float* asrc_i = asrc + (size_t)i * NHEADS * OCD;
        const float* adst_i = adst + (size_t)i * NHEADS * OCD;
        const float* bg_i   = bg + (size_t)i * HD;
        const float* g1_i   = g1 + (size_t)i * HD;
        const float* b1_i   = b1 + (size_t)i * HD;
        const float* ob_i   = ob + (size_t)i * HD;
        const float* g2_i   = g2 + (size_t)i * HD;
        const float* b2_i   = b2 + (size_t)i * HD;
        const float* mb1_i  = mb1 + (size_t)i * 2 * HD;
        const float* mb2_i  = mb2 + (size_t)i * HD;
        const float* g3_i   = g3 + (size_t)i * HD;
        const float* b3_i   = b3 + (size_t)i * HD;
        const short* wcomb_i = wcomb + (size_t)i * 1024 * HD;
        const float* cbias_i = cbias + (size_t)i * 1024;
        const short* ow_ci  = ow_c + (size_t)i * HD * HD;
        const short* mw1_ti = mw1_t + (size_t)i * HD * 2 * HD;
        const short* mw2_ti = mw2_t + (size_t)i * 2 * HD * HD;

        // ---- fused qkv+wg projection -> xq16 ROW-MAJOR ----
        gemm_mfma_kernel<128><<<dim3(1024 / 128, NNODES / GBM), 256, 0, stream>>>(
            xcur16, wcomb_i, cbias_i, nullptr, nullptr, xq16, NNODES, 1024, HD, 0, 1);

        // ---- GAT local branch ----
        gat_scores_kernel<<<(nNH + T - 1) / T, T, 0, stream>>>(xq16 + 768, asrc_i, adst_i, ssrc, sdst);
        gat_agg_ln_kernel<<<NNODES / 4, 256, 0, stream>>>(
            row_ptr, srcs, ssrc, sdst, xq16 + 768, xcur, bg_i, g1_i, b1_i, hbuf);

        // ---- global MHA branch ----
        mha_mfma_kernel<<<dim3(NGRAPH, NHEADS), 256, 0, stream>>>(xq16, b16a);
        // fused: obuf/b16a = LN(mha@ow + ob + xcur)*g2+b2 + hbuf
        gemm_ln_kernel<<<dim3(1, NNODES / 64), 256, 0, stream>>>(
            b16a, ow_ci, ob_i, xcur, g2_i, b2_i, hbuf, obuf, b16a, HD);

        // ---- MLP ----
        gemm_mfma_kernel<128><<<dim3(2 * HD / 128, NNODES / GBM), 256, 0, stream>>>(
            b16a, mw1_ti, mb1_i, nullptr, nullptr, hid16, NNODES, 2 * HD, HD, 1, 0);
        // fused: xcur/xcur16 = LN(hid@mw2 + mb2 + obuf)*g3+b3
        gemm_ln_kernel<<<dim3(1, NNODES / 64), 256, 0, stream>>>(
            hid16, mw2_ti, mb2_i, obuf, g3_i, b3_i, nullptr, xcur, xcur16, 2 * HD);
    }

    // final LN + output projection -> d_out (fp32)
    ln4_kernel<<<NNODES / 4, 256, 0, stream>>>(xcur, nullptr, gf, bf_, nullptr, nullptr, b16a);
    gemm_mfma_kernel<64><<<dim3(OUTDIM / 64, NNODES / GBM), 256, 0, stream>>>(
        b16a, wo_t, bo, nullptr, (float*)d_out, nullptr, NNODES, OUTDIM, HD, 0, 0);
}

// Round 16
// 732.899 us; speedup vs baseline: 1.3683x; 1.0226x over previous
//
#include <hip/hip_runtime.h>
#include <hip/hip_bf16.h>

#define NNODES 16384
#define NEDGES 262144
#define IND    128
#define HD     256
#define OUTDIM 256
#define LAYERS 4
#define NHEADS 8
#define OCD    32
#define NGRAPH 64
#define NBATCH 256
#define XQSTR  1024   // xq16 row stride (row-major: gather/mha consumers)

typedef __hip_bfloat16 bf16;
typedef __attribute__((ext_vector_type(8))) short bf16x8;
typedef __attribute__((ext_vector_type(4))) short s16x4;
typedef __attribute__((ext_vector_type(4))) float f32x4;

__device__ __forceinline__ short bfbits(float v) {
    bf16 h = __float2bfloat16(v);
    return *(short*)&h;
}
__device__ __forceinline__ float b2f(short s) {
    return __uint_as_float(((unsigned)(unsigned short)s) << 16);
}

// blocked bf16 layout (GEMM A/B operands ONLY): X[(r/64)*KC + c/8][r%64][c%8].
__device__ __forceinline__ size_t bidx(int row, int col, int KC) {
    return ((size_t)((row >> 6) * KC + (col >> 3)) << 9) + ((row & 63) << 3) + (col & 7);
}

// direct global->LDS DMA, 16 B/lane; lds base wave-uniform
__device__ __forceinline__ void gload_lds16(const short* g, short* l) {
    __builtin_amdgcn_global_load_lds(
        (const __attribute__((address_space(1))) void*)g,
        (__attribute__((address_space(3))) void*)l, 16, 0, 0);
}

// ---------------- merged prep: zeros + all weight converts (blocked layout) ----
#define PREP_TOTAL (32768 + NNODES*IND + IND*HD + LAYERS*1024*HD + LAYERS*1024 \
                    + LAYERS*HD*HD + LAYERS*HD*2*HD + LAYERS*2*HD*HD + HD*OUTDIM)
__global__ void prep_kernel(const float* __restrict__ x0, const float* __restrict__ wi,
                            const float* __restrict__ inw, const float* __restrict__ wg,
                            const float* __restrict__ inb, const float* __restrict__ ow,
                            const float* __restrict__ mw1, const float* __restrict__ mw2,
                            const float* __restrict__ wo,
                            short* __restrict__ x016, short* __restrict__ wi_t,
                            short* __restrict__ wcomb, float* __restrict__ cbias,
                            short* __restrict__ ow_c, short* __restrict__ mw1_t,
                            short* __restrict__ mw2_t, short* __restrict__ wo_t,
                            int* __restrict__ cnt, int* __restrict__ fill)
{
    int i = blockIdx.x * blockDim.x + threadIdx.x;
    if (i < 32768) {
        if (i < NNODES) cnt[i] = 0; else fill[i - NNODES] = 0;
        return;
    }
    i -= 32768;
    if (i < NNODES * IND) {                // x0 -> blocked [N,128], KC=16
        int row = i / IND, col = i % IND;
        x016[bidx(row, col, 16)] = bfbits(x0[i]);
        return;
    }
    i -= NNODES * IND;
    if (i < IND * HD) {                    // wi [128,256] -> B[n=256][k=128], KC=16
        int k = i / HD, n = i % HD;
        wi_t[bidx(n, k, 16)] = bfbits(wi[i]);
        return;
    }
    i -= IND * HD;
    if (i < LAYERS * 1024 * HD) {          // wcomb rows 0..767=inw, 768..1023=wg^T, KC=32
        int l = i >> 18, r = (i >> 8) & 1023, k = i & 255;
        float v = (r < 768) ? inw[(size_t)l * 768 * 256 + r * 256 + k]
                            : wg[(size_t)l * 256 * 256 + k * 256 + (r - 768)];
        wcomb[((size_t)l << 18) + bidx(r, k, 32)] = bfbits(v);
        return;
    }
    i -= LAYERS * 1024 * HD;
    if (i < LAYERS * 1024) {               // cbias (fp32)
        int l = i >> 10, c = i & 1023;
        cbias[i] = (c < 768) ? inb[l * 768 + c] : 0.f;
        return;
    }
    i -= LAYERS * 1024;
    if (i < LAYERS * HD * HD) {            // ow: B[r=256][k=256], KC=32
        int l = i >> 16, rem = i & 65535, r = rem >> 8, k = rem & 255;
        ow_c[((size_t)l << 16) + bidx(r, k, 32)] = bfbits(ow[i]);
        return;
    }
    i -= LAYERS * HD * HD;
    if (i < LAYERS * HD * 2 * HD) {        // mw1 [k=256][n=512] -> B[n][k], KC=32
        int l = i / (HD * 2 * HD), rem = i % (HD * 2 * HD);
        int k = rem / (2 * HD), n = rem % (2 * HD);
        mw1_t[(size_t)l * HD * 2 * HD + bidx(n, k, 32)] = bfbits(mw1[i]);
        return;
    }
    i -= LAYERS * HD * 2 * HD;
    if (i < LAYERS * 2 * HD * HD) {        // mw2 [k=512][n=256] -> B[n][k], KC=64
        int l = i / (2 * HD * HD), rem = i % (2 * HD * HD);
        int k = rem / HD, n = rem % HD;
        mw2_t[(size_t)l * 2 * HD * HD + bidx(n, k, 64)] = bfbits(mw2[i]);
        return;
    }
    i -= LAYERS * 2 * HD * HD;
    if (i < HD * OUTDIM) {                 // wo [k=256][n=256] -> B[n][k], KC=32
        int k = i / OUTDIM, n = i % OUTDIM;
        wo_t[bidx(n, k, 32)] = bfbits(wo[i]);
    }
}

// ---------------- CSR build ----------------------------------------------------
__global__ void hist_kernel(const int* __restrict__ dst, int* __restrict__ cnt)
{
    int e = blockIdx.x * blockDim.x + threadIdx.x;
    if (e < NEDGES) atomicAdd(&cnt[dst[e]], 1);
}

__global__ void scan_kernel(const int* __restrict__ cnt, int* __restrict__ row_ptr)
{
    __shared__ int part[256];
    int t = threadIdx.x;
    const int PER = NNODES / 256;
    int base = t * PER;
    int s = 0;
    for (int i = 0; i < PER; i++) s += cnt[base + i];
    part[t] = s;
    __syncthreads();
    for (int off = 1; off < 256; off <<= 1) {
        int v = (t >= off) ? part[t - off] : 0;
        __syncthreads();
        part[t] += v;
        __syncthreads();
    }
    int run = (t == 0) ? 0 : part[t - 1];
    for (int i = 0; i < PER; i++) { row_ptr[base + i] = run; run += cnt[base + i]; }
    if (t == 255) row_ptr[NNODES] = run;
}

__global__ void scatter_kernel(const int* __restrict__ src, const int* __restrict__ dst,
                               const int* __restrict__ row_ptr, int* __restrict__ fill,
                               int* __restrict__ srcs)
{
    int e = blockIdx.x * blockDim.x + threadIdx.x;
    if (e >= NEDGES) return;
    int d = dst[e];
    int pos = row_ptr[d] + atomicAdd(&fill[d], 1);
    srcs[pos] = src[e];
}

// ---------------- GAT per-node attention scores (row-major xw16) ---------------
__global__ void gat_scores_kernel(const short* __restrict__ xw16,
                                  const float* __restrict__ asrc, const float* __restrict__ adst,
                                  float* __restrict__ ssrc, float* __restrict__ sdst)
{
    int i = blockIdx.x * blockDim.x + threadIdx.x;   // n*NHEADS + h
    if (i >= NNODES * NHEADS) return;
    int n = i >> 3, h = i & 7;
    const bf16x8* xr = (const bf16x8*)(xw16 + (size_t)n * XQSTR + h * OCD);
    float s1 = 0.f, s2 = 0.f;
#pragma unroll
    for (int g = 0; g < 4; g++) {
        bf16x8 v8 = xr[g];
#pragma unroll
        for (int j = 0; j < 8; j++) {
            float v = b2f(v8[j]);
            int d = g * 8 + j;
            s1 += v * asrc[h * OCD + d];
            s2 += v * adst[h * OCD + d];
        }
    }
    ssrc[i] = s1;
    sdst[i] = s2;
}

// ---------------- fused GAT softmax + aggregation + LayerNorm ------------------
// Wave-per-node, row-major 8 B gathers, 8 loads in flight, shuffle LN.
__global__ __launch_bounds__(256)
void gat_agg_ln_kernel(const int* __restrict__ row_ptr, const int* __restrict__ srcs,
                       const float* __restrict__ ssrc, const float* __restrict__ sdst,
                       const short* __restrict__ xw16, const float* __restrict__ xcur,
                       const float* __restrict__ colbias, const float* __restrict__ gamma,
                       const float* __restrict__ beta, float* __restrict__ out)
{
    int wave = threadIdx.x >> 6, lane = threadIdx.x & 63;
    int n = blockIdx.x * 4 + wave;
    int c0 = lane << 2;            // 4 channels per lane
    int h = c0 >> 5;               // head of all 4 channels
    int start = row_ptr[n];
    int deg = row_ptr[n + 1] - start;
    float sd = sdst[n * NHEADS + h];

    float ax = 0.f, ay = 0.f, az = 0.f, aw = 0.f, l = 0.f;
    int j = 0;
    for (; j + 8 <= deg; j += 8) {
        int e[8];
        s16x4 r[8];
        float sc[8];
#pragma unroll
        for (int u = 0; u < 8; u++) e[u] = srcs[start + j + u];
#pragma unroll
        for (int u = 0; u < 8; u++) r[u] = *(const s16x4*)&xw16[(size_t)e[u] * XQSTR + c0];
#pragma unroll
        for (int u = 0; u < 8; u++) sc[u] = ssrc[e[u] * NHEADS + h];
#pragma unroll
        for (int u = 0; u < 8; u++) {
            float a = sc[u] + sd;
            a = a > 0.f ? a : 0.2f * a;
            float p = __expf(a);
            l += p;
            ax += p * b2f(r[u][0]);
            ay += p * b2f(r[u][1]);
            az += p * b2f(r[u][2]);
            aw += p * b2f(r[u][3]);
        }
    }
    for (; j < deg; j++) {
        int e0 = srcs[start + j];
        s16x4 r0 = *(const s16x4*)&xw16[(size_t)e0 * XQSTR + c0];
        float a0 = ssrc[e0 * NHEADS + h] + sd; a0 = a0 > 0.f ? a0 : 0.2f * a0;
        float p0 = __expf(a0);
        l += p0;
        ax += p0 * b2f(r0[0]); ay += p0 * b2f(r0[1]);
        az += p0 * b2f(r0[2]); aw += p0 * b2f(r0[3]);
    }
    float invl = deg ? 1.f / l : 0.f;
    size_t base = (size_t)n * HD + c0;
    float4 x4 = *(const float4*)&xcur[base];
    float4 cb = *(const float4*)&colbias[c0];
    float4 v;
    v.x = ax * invl + x4.x + cb.x;
    v.y = ay * invl + x4.y + cb.y;
    v.z = az * invl + x4.z + cb.z;
    v.w = aw * invl + x4.w + cb.w;
    float s = v.x + v.y + v.z + v.w;
    float q = v.x * v.x + v.y * v.y + v.z * v.z + v.w * v.w;
#pragma unroll
    for (int off = 1; off < 64; off <<= 1) {
        s += __shfl_xor(s, off);
        q += __shfl_xor(q, off);
    }
    float mean = s * (1.f / HD);
    float var  = fmaxf(q * (1.f / HD) - mean * mean, 0.f);
    float inv  = rsqrtf(var + 1e-5f);
    float4 g  = *(const float4*)&gamma[c0];
    float4 bt = *(const float4*)&beta[c0];
    float4 y;
    y.x = (v.x - mean) * inv * g.x + bt.x;
    y.y = (v.y - mean) * inv * g.y + bt.y;
    y.z = (v.z - mean) * inv * g.z + bt.z;
    y.w = (v.w - mean) * inv * g.w + bt.w;
    *(float4*)&out[base] = y;
}

// ---------------- bf16 MFMA GEMM (blocked A/B, double-buffered LDS) ------------
// DMA for tile t+1 issued right after the barrier of tile t -> overlaps MFMA.
#define GBM 128
#define GBK 32

template<int TN>
__global__ __launch_bounds__(256)
void gemm_mfma_kernel(const short* __restrict__ A16, const short* __restrict__ B16,
                      const float* __restrict__ bias, const float* __restrict__ resid,
                      float* __restrict__ Cf, short* __restrict__ C16,
                      int M, int Nc, int K, int relu, int c16rm)
{
    constexpr int NTF = TN / 32;          // n-frags per wave
    constexpr int ASZ = GBM * GBK;        // 4096 shorts
    constexpr int BSZ = TN * GBK;
    __shared__ short As[2 * ASZ];
    __shared__ short Bs[2 * BSZ];
    int tid = threadIdx.x;
    int wid = tid >> 6, lane = tid & 63;
    int quad = lane >> 4, l16 = lane & 15;
    int wm = wid >> 1, wn = wid & 1;
    int rowBase = blockIdx.y * GBM;
    int colBase = blockIdx.x * TN;
    int KC = K >> 3;

    f32x4 acc[4][NTF];
#pragma unroll
    for (int mt = 0; mt < 4; mt++)
#pragma unroll
        for (int nt = 0; nt < NTF; nt++) acc[mt][nt] = (f32x4)(0.f);

    const short* Ag0 = A16 + (((size_t)(blockIdx.y * 2 + 0) * KC + wid) << 9) + lane * 8;
    const short* Ag1 = A16 + (((size_t)(blockIdx.y * 2 + 1) * KC + wid) << 9) + lane * 8;
    const short* Bg0 = B16 + (((size_t)((colBase >> 6) + 0) * KC + wid) << 9) + lane * 8;
    const short* Bg1 = (TN == 128) ?
        B16 + (((size_t)((colBase >> 6) + 1) * KC + wid) << 9) + lane * 8 : nullptr;
    short* AsD0 = As + (wid * 128 + 0) * 8;
    short* AsD1 = As + (wid * 128 + 64) * 8;
    short* BsD0 = Bs + (wid * TN) * 8;
    short* BsD1 = Bs + (wid * TN + 64) * 8;

    int TT = K >> 5;
    // prologue: DMA tile 0 into buffer 0
    gload_lds16(Ag0, AsD0);
    gload_lds16(Ag1, AsD1);
    gload_lds16(Bg0, BsD0);
    if (TN == 128) gload_lds16(Bg1, BsD1);

    for (int t = 0; t < TT; t++) {
        __syncthreads();                   // waits DMA of tile t (vmcnt drain)
        int cur = t & 1;
        if (t + 1 < TT) {                  // prefetch tile t+1 -> other buffer
            int nb = (t + 1) & 1;
            gload_lds16(Ag0 + (t + 1) * 2048, AsD0 + nb * ASZ);
            gload_lds16(Ag1 + (t + 1) * 2048, AsD1 + nb * ASZ);
            gload_lds16(Bg0 + (t + 1) * 2048, BsD0 + nb * BSZ);
            if (TN == 128) gload_lds16(Bg1 + (t + 1) * 2048, BsD1 + nb * BSZ);
        }
        const short* Ab = As + cur * ASZ;
        const short* Bb = Bs + cur * BSZ;
        bf16x8 aF[4], bF[NTF];
#pragma unroll
        for (int mt = 0; mt < 4; mt++)
            aF[mt] = *(bf16x8*)&Ab[(quad * 128 + wm * 64 + mt * 16 + l16) * 8];
#pragma unroll
        for (int nt = 0; nt < NTF; nt++)
            bF[nt] = *(bf16x8*)&Bb[(quad * TN + wn * (TN / 2) + nt * 16 + l16) * 8];
#pragma unroll
        for (int mt = 0; mt < 4; mt++)
#pragma unroll
            for (int nt = 0; nt < NTF; nt++)
                acc[mt][nt] = __builtin_amdgcn_mfma_f32_16x16x32_bf16(
                    bF[nt], aF[mt], acc[mt][nt], 0, 0, 0);   // swapped operands
    }

#pragma unroll
    for (int mt = 0; mt < 4; mt++) {
        int row = rowBase + wm * 64 + mt * 16 + l16;
#pragma unroll
        for (int nt = 0; nt < NTF; nt++) {
            int col0 = colBase + wn * (TN / 2) + nt * 16 + quad * 4;
            f32x4 v = acc[mt][nt];
            if (bias) {
                float4 b4 = *(const float4*)&bias[col0];
                v[0] += b4.x; v[1] += b4.y; v[2] += b4.z; v[3] += b4.w;
            }
            if (resid) {
                float4 r4 = *(const float4*)&resid[(size_t)row * Nc + col0];
                v[0] += r4.x; v[1] += r4.y; v[2] += r4.z; v[3] += r4.w;
            }
            if (relu) {
                v[0] = fmaxf(v[0], 0.f); v[1] = fmaxf(v[1], 0.f);
                v[2] = fmaxf(v[2], 0.f); v[3] = fmaxf(v[3], 0.f);
            }
            if (Cf) {
                float4 o; o.x = v[0]; o.y = v[1]; o.z = v[2]; o.w = v[3];
                *(float4*)&Cf[(size_t)row * Nc + col0] = o;
            }
            if (C16) {
                s16x4 o;
                o[0] = bfbits(v[0]); o[1] = bfbits(v[1]);
                o[2] = bfbits(v[2]); o[3] = bfbits(v[3]);
                if (c16rm) *(s16x4*)&C16[(size_t)row * Nc + col0] = o;
                else       *(s16x4*)&C16[bidx(row, col0, Nc >> 3)] = o;
            }
        }
    }
}

// ---------------- fused GEMM + residual + LayerNorm (+postadd) -----------------
// 64x256 tile, double-buffered (grid=256 -> 1 block/CU, pipelining is the only
// latency hiding available). out16 blocked; 2-shuffle LN.
__global__ __launch_bounds__(256)
void gemm_ln_kernel(const short* __restrict__ A16, const short* __restrict__ B16,
                    const float* __restrict__ bias, const float* __restrict__ resid,
                    const float* __restrict__ gamma, const float* __restrict__ beta,
                    const float* __restrict__ postadd,
                    float* __restrict__ outf, short* __restrict__ out16, int K)
{
    constexpr int ASZ = 64 * GBK;         // 2048 shorts
    constexpr int BSZ = 256 * GBK;        // 8192 shorts
    __shared__ short As[2 * ASZ];
    __shared__ short Bs[2 * BSZ];
    int tid = threadIdx.x;
    int wid = tid >> 6, lane = tid & 63;
    int quad = lane >> 4, l16 = lane & 15;
    int rowBase = blockIdx.y * 64;
    int KC = K >> 3;

    f32x4 acc[16];
#pragma unroll
    for (int nt = 0; nt < 16; nt++) acc[nt] = (f32x4)(0.f);

    const short* Ag  = A16 + (((size_t)blockIdx.y * KC + wid) << 9) + lane * 8;
    const short* Bg0 = B16 + (((size_t)0 * KC + wid) << 9) + lane * 8;
    const short* Bg1 = B16 + (((size_t)1 * KC + wid) << 9) + lane * 8;
    const short* Bg2 = B16 + (((size_t)2 * KC + wid) << 9) + lane * 8;
    const short* Bg3 = B16 + (((size_t)3 * KC + wid) << 9) + lane * 8;
    short* AsD  = As + (wid * 64) * 8;
    short* BsD0 = Bs + (wid * 256 + 0) * 8;
    short* BsD1 = Bs + (wid * 256 + 64) * 8;
    short* BsD2 = Bs + (wid * 256 + 128) * 8;
    short* BsD3 = Bs + (wid * 256 + 192) * 8;

    int TT = K >> 5;
    gload_lds16(Ag, AsD);
    gload_lds16(Bg0, BsD0);
    gload_lds16(Bg1, BsD1);
    gload_lds16(Bg2, BsD2);
    gload_lds16(Bg3, BsD3);

    for (int t = 0; t < TT; t++) {
        __syncthreads();
        int cur = t & 1;
        if (t + 1 < TT) {
            int nb = (t + 1) & 1;
            gload_lds16(Ag + (t + 1) * 2048, AsD + nb * ASZ);
            gload_lds16(Bg0 + (t + 1) * 2048, BsD0 + nb * BSZ);
            gload_lds16(Bg1 + (t + 1) * 2048, BsD1 + nb * BSZ);
            gload_lds16(Bg2 + (t + 1) * 2048, BsD2 + nb * BSZ);
            gload_lds16(Bg3 + (t + 1) * 2048, BsD3 + nb * BSZ);
        }
        const short* Ab = As + cur * ASZ;
        const short* Bb = Bs + cur * BSZ;
        bf16x8 aF = *(bf16x8*)&Ab[(quad * 64 + wid * 16 + l16) * 8];
#pragma unroll
        for (int nt = 0; nt < 16; nt++) {
            bf16x8 bF = *(bf16x8*)&Bb[(quad * 256 + nt * 16 + l16) * 8];
            acc[nt] = __builtin_amdgcn_mfma_f32_16x16x32_bf16(bF, aF, acc[nt], 0, 0, 0);
        }
    }

    int row = rowBase + wid * 16 + l16;
    float s = 0.f, q = 0.f;
#pragma unroll
    for (int nt = 0; nt < 16; nt++) {
        int col0 = nt * 16 + quad * 4;
        f32x4 v = acc[nt];
        float4 b4 = *(const float4*)&bias[col0];
        float4 r4 = *(const float4*)&resid[(size_t)row * HD + col0];
        v[0] += b4.x + r4.x; v[1] += b4.y + r4.y;
        v[2] += b4.z + r4.z; v[3] += b4.w + r4.w;
        acc[nt] = v;
        s += (v[0] + v[1]) + (v[2] + v[3]);
        q += (v[0] * v[0] + v[1] * v[1]) + (v[2] * v[2] + v[3] * v[3]);
    }
    s += __shfl_xor(s, 16); s += __shfl_xor(s, 32);
    q += __shfl_xor(q, 16); q += __shfl_xor(q, 32);
    float mean = s * (1.f / HD);
    float var  = fmaxf(q * (1.f / HD) - mean * mean, 0.f);
    float inv  = rsqrtf(var + 1e-5f);
#pragma unroll
    for (int nt = 0; nt < 16; nt++) {
        int col0 = nt * 16 + quad * 4;
        f32x4 v = acc[nt];
        float4 g4 = *(const float4*)&gamma[col0];
        float4 bt = *(const float4*)&beta[col0];
        float4 y;
        y.x = (v[0] - mean) * inv * g4.x + bt.x;
        y.y = (v[1] - mean) * inv * g4.y + bt.y;
        y.z = (v[2] - mean) * inv * g4.z + bt.z;
        y.w = (v[3] - mean) * inv * g4.w + bt.w;
        if (postadd) {
            float4 p4 = *(const float4*)&postadd[(size_t)row * HD + col0];
            y.x += p4.x; y.y += p4.y; y.z += p4.z; y.w += p4.w;
        }
        *(float4*)&outf[(size_t)row * HD + col0] = y;
        s16x4 o;
        o[0] = bfbits(y.x); o[1] = bfbits(y.y); o[2] = bfbits(y.z); o[3] = bfbits(y.w);
        *(s16x4*)&out16[bidx(row, col0, 32)] = o;
    }
}

// ---------------- LayerNorm: wave-per-row, float4, shuffle-only ----------------
__global__ __launch_bounds__(256)
void ln4_kernel(const float* __restrict__ in, const float* __restrict__ res,
                const float* __restrict__ gamma, const float* __restrict__ beta,
                const float* __restrict__ postadd,
                float* __restrict__ outf, short* __restrict__ out16)
{
    int wave = threadIdx.x >> 6, lane = threadIdx.x & 63;
    int row = blockIdx.x * 4 + wave;
    size_t base = (size_t)row * HD + lane * 4;
    float4 v = *(const float4*)&in[base];
    if (res) {
        float4 r = *(const float4*)&res[base];
        v.x += r.x; v.y += r.y; v.z += r.z; v.w += r.w;
    }
    float s = v.x + v.y + v.z + v.w;
    float q = v.x * v.x + v.y * v.y + v.z * v.z + v.w * v.w;
#pragma unroll
    for (int off = 1; off < 64; off <<= 1) {
        s += __shfl_xor(s, off);
        q += __shfl_xor(q, off);
    }
    float mean = s * (1.f / HD);
    float var  = fmaxf(q * (1.f / HD) - mean * mean, 0.f);
    float inv  = rsqrtf(var + 1e-5f);
    float4 g  = *(const float4*)&gamma[lane * 4];
    float4 bt = *(const float4*)&beta[lane * 4];
    float4 y;
    y.x = (v.x - mean) * inv * g.x + bt.x;
    y.y = (v.y - mean) * inv * g.y + bt.y;
    y.z = (v.z - mean) * inv * g.z + bt.z;
    y.w = (v.w - mean) * inv * g.w + bt.w;
    if (postadd) {
        float4 p = *(const float4*)&postadd[base];
        y.x += p.x; y.y += p.y; y.z += p.z; y.w += p.w;
    }
    if (outf) *(float4*)&outf[base] = y;
    if (out16) {
        s16x4 o;
        o[0] = bfbits(y.x); o[1] = bfbits(y.y); o[2] = bfbits(y.z); o[3] = bfbits(y.w);
        *(s16x4*)&out16[bidx(row, lane * 4, 32)] = o;
    }
}

// ---------------- MFMA per-graph MHA (row-major qkv16, stride XQSTR) -----------
#define PSTR 72                       // slot stride 9 (x16B) == 1 mod 8 -> conflict-free
__global__ __launch_bounds__(256)
void mha_mfma_kernel(const short* __restrict__ qkv16, short* __restrict__ o16)
{
    __shared__ short smem[4 * 64 * PSTR + 32 * PSTR];   // P + V^T
    short* VT = smem + 4 * 64 * PSTR;

    int b = blockIdx.x, h = blockIdx.y;
    int tid = threadIdx.x;
    int wid = tid >> 6, lane = tid & 63;
    int quad = lane >> 4, l16 = lane & 15;
    int base = b * NBATCH;
    int qrow0 = wid * 64;
    short* Pme = smem + wid * 64 * PSTR;

    const float scale2 = 0.17677669529663687f * 1.4426950408889634f; // 1/sqrt(32)*log2(e)

    bf16x8 qA[4];
#pragma unroll
    for (int mt = 0; mt < 4; mt++)
        qA[mt] = *(const bf16x8*)&qkv16[(size_t)(base + qrow0 + mt * 16 + l16) * XQSTR + h * 32 + quad * 8];

    f32x4 accO[4][2];
#pragma unroll
    for (int mt = 0; mt < 4; mt++)
#pragma unroll
        for (int dt = 0; dt < 2; dt++) accO[mt][dt] = (f32x4)(0.f);
    float lsum[4][4];
#pragma unroll
    for (int mt = 0; mt < 4; mt++)
#pragma unroll
        for (int r = 0; r < 4; r++) lsum[mt][r] = 0.f;

    for (int c = 0; c < 4; c++) {                  // 4 key-chunks of 64
        __syncthreads();
        {
            int key = tid >> 2, dq = (tid & 3) * 8;
            bf16x8 v = *(const bf16x8*)&qkv16[(size_t)(base + c * 64 + key) * XQSTR + 512 + h * 32 + dq];
#pragma unroll
            for (int j = 0; j < 8; j++) VT[(dq + j) * PSTR + key] = v[j];
        }
        __syncthreads();
        bf16x8 kB[4];
#pragma unroll
        for (int kt = 0; kt < 4; kt++)
            kB[kt] = *(const bf16x8*)&qkv16[(size_t)(base + c * 64 + kt * 16 + l16) * XQSTR + 256 + h * 32 + quad * 8];
#pragma unroll
        for (int mt = 0; mt < 4; mt++) {
#pragma unroll
            for (int kt = 0; kt < 4; kt++) {
                f32x4 s = __builtin_amdgcn_mfma_f32_16x16x32_bf16(qA[mt], kB[kt], (f32x4)(0.f), 0, 0, 0);
#pragma unroll
                for (int r = 0; r < 4; r++) {
                    float p = exp2f(s[r] * scale2);
                    lsum[mt][r] += p;
                    Pme[(mt * 16 + quad * 4 + r) * PSTR + kt * 16 + l16] = bfbits(p);
                }
            }
        }
        __syncthreads();
#pragma unroll
        for (int mt = 0; mt < 4; mt++) {
#pragma unroll
            for (int ks = 0; ks < 2; ks++) {
                bf16x8 pA = *(bf16x8*)&Pme[(mt * 16 + l16) * PSTR + ks * 32 + quad * 8];
#pragma unroll
                for (int dt = 0; dt < 2; dt++) {
                    bf16x8 vB = *(bf16x8*)&VT[(dt * 16 + l16) * PSTR + ks * 32 + quad * 8];
                    accO[mt][dt] = __builtin_amdgcn_mfma_f32_16x16x32_bf16(pA, vB, accO[mt][dt], 0, 0, 0);
                }
            }
        }
    }
#pragma unroll
    for (int mt = 0; mt < 4; mt++)
#pragma unroll
        for (int r = 0; r < 4; r++) {
            float v = lsum[mt][r];
            v += __shfl_xor(v, 1);
            v += __shfl_xor(v, 2);
            v += __shfl_xor(v, 4);
            v += __shfl_xor(v, 8);
            lsum[mt][r] = v;
        }
    // o16 (b16a) is a GEMM A-operand consumer -> blocked write
#pragma unroll
    for (int mt = 0; mt < 4; mt++)
#pragma unroll
        for (int dt = 0; dt < 2; dt++)
#pragma unroll
            for (int r = 0; r < 4; r++) {
                int row = base + qrow0 + mt * 16 + quad * 4 + r;
                int col = h * 32 + dt * 16 + l16;
                o16[bidx(row, col, 32)] = bfbits(accO[mt][dt][r] / lsum[mt][r]);
            }
}

// ------------------------------------------------------------------------------
extern "C" void kernel_launch(void* const* d_in, const int* in_sizes, int n_in,
                              void* d_out, int out_size, void* d_ws, size_t ws_size,
                              hipStream_t stream)
{
    const float* x0   = (const float*)d_in[0];
    const int*   ei   = (const int*)d_in[1];
    const float* wi   = (const float*)d_in[2];
    const float* bi   = (const float*)d_in[3];
    const float* wg   = (const float*)d_in[4];
    const float* asrc = (const float*)d_in[5];
    const float* adst = (const float*)d_in[6];
    const float* bg   = (const float*)d_in[7];
    const float* g1   = (const float*)d_in[8];
    const float* b1   = (const float*)d_in[9];
    const float* inw  = (const float*)d_in[10];
    const float* inb  = (const float*)d_in[11];
    const float* ow   = (const float*)d_in[12];
    const float* ob   = (const float*)d_in[13];
    const float* g2   = (const float*)d_in[14];
    const float* b2   = (const float*)d_in[15];
    const float* mw1  = (const float*)d_in[16];
    const float* mb1  = (const float*)d_in[17];
    const float* mw2  = (const float*)d_in[18];
    const float* mb2  = (const float*)d_in[19];
    const float* g3   = (const float*)d_in[20];
    const float* b3   = (const float*)d_in[21];
    const float* gf   = (const float*)d_in[22];
    const float* bf_  = (const float*)d_in[23];
    const float* wo   = (const float*)d_in[24];
    const float* bo   = (const float*)d_in[25];

    const int* srcI = ei;
    const int* dstI = ei + NEDGES;

    // ---- workspace layout ----
    const size_t NH = (size_t)NNODES * HD;           // 4,194,304
    float* ws   = (float*)d_ws;
    float* xcur = ws;                // [N,H] fp32
    float* xw   = xcur + NH;         // [N,H] fp32 (layout stability)
    float* hbuf = xw + NH;           // [N,H] fp32
    float* obuf = hbuf + NH;         // [N,H] fp32
    float* qkvb = obuf + NH;         // bf16 [N,1024] ROW-MAJOR (gather/mha)
    int*   srcs    = (int*)(qkvb + 3 * NH);          // [E]
    int*   row_ptr = srcs + NEDGES;                  // [N+1]
    int*   cnt     = row_ptr + NNODES + 1;           // [N]
    int*   fill    = cnt + NNODES;                   // [N]
    float* ssrc    = (float*)(fill + NNODES);        // [N,8]
    float* sdst    = ssrc + (size_t)NNODES * NHEADS; // [N,8]
    // bf16 (short) region — GEMM A-operands + weights BLOCKED; xq16 row-major
    short* xq16   = (short*)qkvb;                    // [N,1024] row-major
    short* x016   = (short*)(sdst + (size_t)NNODES * NHEADS);  // [N,128] blocked KC=16
    short* xcur16 = x016 + (size_t)NNODES * IND;     // [N,H] blocked KC=32
    short* b16a   = xcur16 + NH;                     // [N,H] blocked KC=32
    short* hid16  = b16a + NH;                       // [N,2H] blocked KC=64
    // bf16 weights (blocked)
    short* wi_t  = hid16 + 2 * NH;                         // [256,128] KC=16
    short* wcomb = wi_t + (size_t)HD * IND;                // 4x[1024,256] KC=32
    short* ow_c  = wcomb + (size_t)LAYERS * 1024 * HD;     // 4x[256,256] KC=32
    short* mw1_t = ow_c + (size_t)LAYERS * HD * HD;        // 4x[512,256] KC=32
    short* mw2_t = mw1_t + (size_t)LAYERS * HD * 2 * HD;   // 4x[256,512] KC=64
    short* wo_t  = mw2_t + (size_t)LAYERS * 2 * HD * HD;   // [256,256] KC=32
    float* cbias = (float*)(wo_t + (size_t)HD * OUTDIM);   // 4x[1024] fp32

    const int T = 256;
    const int nNH = NNODES * NHEADS;

    // ---- merged prep (zeros + all weight converts) ----
    prep_kernel<<<(PREP_TOTAL + T - 1) / T, T, 0, stream>>>(
        x0, wi, inw, wg, inb, ow, mw1, mw2, wo,
        x016, wi_t, wcomb, cbias, ow_c, mw1_t, mw2_t, wo_t, cnt, fill);

    // ---- CSR build ----
    hist_kernel<<<(NEDGES + T - 1) / T, T, 0, stream>>>(dstI, cnt);
    scan_kernel<<<1, 256, 0, stream>>>(cnt, row_ptr);
    scatter_kernel<<<(NEDGES + T - 1) / T, T, 0, stream>>>(srcI, dstI, row_ptr, fill, srcs);

    // x = relu(x0 @ wi + bi) -> xcur fp32 + xcur16 bf16(blocked)
    gemm_mfma_kernel<64><<<dim3(HD / 64, NNODES / GBM), 256, 0, stream>>>(
        x016, wi_t, bi, nullptr, xcur, xcur16, NNODES, HD, IND, 1, 0);

    for (int i = 0; i < LAYERS; i++) {
        const float* asrc_i = asrc + (size_t)i * NHEADS * OCD;
        const float* adst_i = adst + (size_t)i * NHEADS * OCD;
        const float* bg_i   = bg + (size_t)i * HD;
        const float* g1_i   = g1 + (size_t)i * HD;
        const float* b1_i   = b1 + (size_t)i * HD;
        const float* ob_i   = ob + (size_t)i * HD;
        const float* g2_i   = g2 + (size_t)i * HD;
        const float* b2_i   = b2 + (size_t)i * HD;
        const float* mb1_i  = mb1 + (size_t)i * 2 * HD;
        const float* mb2_i  = mb2 + (size_t)i * HD;
        const float* g3_i   = g3 + (size_t)i * HD;
        const float* b3_i   = b3 + (size_t)i * HD;
        const short* wcomb_i = wcomb + (size_t)i * 1024 * HD;
        const float* cbias_i = cbias + (size_t)i * 1024;
        const short* ow_ci  = ow_c + (size_t)i * HD * HD;
        const short* mw1_ti = mw1_t + (size_t)i * HD * 2 * HD;
        const short* mw2_ti = mw2_t + (size_t)i * 2 * HD * HD;

        // ---- fused qkv+wg projection -> xq16 ROW-MAJOR ----
        gemm_mfma_kernel<128><<<dim3(1024 / 128, NNODES / GBM), 256, 0, stream>>>(
            xcur16, wcomb_i, cbias_i, nullptr, nullptr, xq16, NNODES, 1024, HD, 0, 1);

        // ---- GAT local branch ----
        gat_scores_kernel<<<(nNH + T - 1) / T, T, 0, stream>>>(xq16 + 768, asrc_i, adst_i, ssrc, sdst);
        gat_agg_ln_kernel<<<NNODES / 4, 256, 0, stream>>>(
            row_ptr, srcs, ssrc, sdst, xq16 + 768, xcur, bg_i, g1_i, b1_i, hbuf);

        // ---- global MHA branch ----
        mha_mfma_kernel<<<dim3(NGRAPH, NHEADS), 256, 0, stream>>>(xq16, b16a);
        // fused: obuf/b16a = LN(mha@ow + ob + xcur)*g2+b2 + hbuf
        gemm_ln_kernel<<<dim3(1, NNODES / 64), 256, 0, stream>>>(
            b16a, ow_ci, ob_i, xcur, g2_i, b2_i, hbuf, obuf, b16a, HD);

        // ---- MLP ----
        gemm_mfma_kernel<128><<<dim3(2 * HD / 128, NNODES / GBM), 256, 0, stream>>>(
            b16a, mw1_ti, mb1_i, nullptr, nullptr, hid16, NNODES, 2 * HD, HD, 1, 0);
        // fused: xcur/xcur16 = LN(hid@mw2 + mb2 + obuf)*g3+b3
        gemm_ln_kernel<<<dim3(1, NNODES / 64), 256, 0, stream>>>(
            hid16, mw2_ti, mb2_i, obuf, g3_i, b3_i, nullptr, xcur, xcur16, 2 * HD);
    }

    // final LN + output projection -> d_out (fp32)
    ln4_kernel<<<NNODES / 4, 256, 0, stream>>>(xcur, nullptr, gf, bf_, nullptr, nullptr, b16a);
    gemm_mfma_kernel<64><<<dim3(OUTDIM / 64, NNODES / GBM), 256, 0, stream>>>(
        b16a, wo_t, bo, nullptr, (float*)d_out, nullptr, NNODES, OUTDIM, HD, 0, 0);
}